// Round 1
// baseline (2539.076 us; speedup 1.0000x reference)
//
#include <hip/hip_runtime.h>
#include <hip/hip_bf16.h>

// PPI GAT: 3-layer graph attention network, N=50000 nodes, E=800000 edges (+N self loops).
// Strategy: build CSR-by-dst on device each launch (cheap), then per layer:
//   GEMM (fp32 tiled) -> per-node attention logits -> wave-per-(node,head) softmax-aggregate.
// Workspace budget ~160 MB.

#define NODES 50000
#define EDGES 800000

// ---------------- CSR build ----------------

__global__ void fill_ones_kernel(int* __restrict__ deg, int n) {
    int i = blockIdx.x * blockDim.x + threadIdx.x;
    if (i < n) deg[i] = 1;  // self-loop
}

__global__ void hist_kernel(const int* __restrict__ dst, int* __restrict__ deg, int E) {
    int e = blockIdx.x * blockDim.x + threadIdx.x;
    if (e < E) atomicAdd(&deg[dst[e]], 1);
}

__global__ void scan_kernel(const int* __restrict__ deg, int* __restrict__ row_ptr,
                            int* __restrict__ cursor, int n) {
    __shared__ int s_ws[16];
    __shared__ int s_off;
    __shared__ int s_total;
    int tid = threadIdx.x, lane = tid & 63, wid = tid >> 6;
    if (tid == 0) s_off = 0;
    __syncthreads();
    for (int base = 0; base < n; base += 1024) {
        int i = base + tid;
        int v = (i < n) ? deg[i] : 0;
        int incl = v;
        #pragma unroll
        for (int ofs = 1; ofs < 64; ofs <<= 1) {
            int t = __shfl_up(incl, ofs);
            if (lane >= ofs) incl += t;
        }
        if (lane == 63) s_ws[wid] = incl;
        __syncthreads();
        if (tid == 0) {
            int run = 0;
            for (int k = 0; k < 16; k++) { int t = s_ws[k]; s_ws[k] = run; run += t; }
            s_total = run;
        }
        __syncthreads();
        int excl = incl - v + s_ws[wid] + s_off;
        if (i < n) { row_ptr[i] = excl; cursor[i] = excl; }
        __syncthreads();
        if (tid == 0) s_off += s_total;
        __syncthreads();
    }
    if (tid == 0) row_ptr[n] = s_off;
}

__global__ void scatter_kernel(const int* __restrict__ src, const int* __restrict__ dst,
                               int E, int n, int* __restrict__ cursor, int* __restrict__ csr_src) {
    int e = blockIdx.x * blockDim.x + threadIdx.x;
    if (e < E) {
        int d = dst[e];
        int p = atomicAdd(&cursor[d], 1);
        csr_src[p] = src[e];
    } else if (e < E + n) {
        int i = e - E;
        int p = atomicAdd(&cursor[i], 1);
        csr_src[p] = i;  // self-loop
    }
}

// ---------------- fp32 tiled GEMM: C[M,N] = A[M,K] @ W[K,N] ----------------
// A row stride = K; W row stride = ldw (for column-slicing W3); C row stride = ldc.

#define BM 64
#define BN 64
#define BK 16

__global__ __launch_bounds__(256) void gemm_kernel(
    const float* __restrict__ A, const float* __restrict__ W, float* __restrict__ C,
    int M, int N, int K, int ldw, int ldc) {
    __shared__ float As[BK][BM + 1];
    __shared__ float Bs[BK][BN + 1];
    int tid = threadIdx.x;
    int tx = tid & 15, ty = tid >> 4;
    int bm = blockIdx.x * BM;
    int bn = blockIdx.y * BN;
    float acc[4][4] = {};
    for (int k0 = 0; k0 < K; k0 += BK) {
        #pragma unroll
        for (int l = 0; l < 4; l++) {
            int idx = tid + l * 256;
            int m = idx / BK;
            int k = idx % BK;
            int gm = bm + m;
            As[k][m] = (gm < M) ? A[(size_t)gm * K + k0 + k] : 0.f;
        }
        #pragma unroll
        for (int l = 0; l < 4; l++) {
            int idx = tid + l * 256;
            int k = idx / BN;
            int nn = idx % BN;
            int gn = bn + nn;
            Bs[k][nn] = (gn < N) ? W[(size_t)(k0 + k) * ldw + gn] : 0.f;
        }
        __syncthreads();
        #pragma unroll
        for (int k = 0; k < BK; k++) {
            float a[4], b[4];
            #pragma unroll
            for (int i = 0; i < 4; i++) a[i] = As[k][ty * 4 + i];
            #pragma unroll
            for (int j = 0; j < 4; j++) b[j] = Bs[k][tx * 4 + j];
            #pragma unroll
            for (int i = 0; i < 4; i++)
                #pragma unroll
                for (int j = 0; j < 4; j++) acc[i][j] += a[i] * b[j];
        }
        __syncthreads();
    }
    for (int i = 0; i < 4; i++) {
        int gm = bm + ty * 4 + i;
        if (gm >= M) continue;
        for (int j = 0; j < 4; j++) {
            int gn = bn + tx * 4 + j;
            if (gn < N) C[(size_t)gm * ldc + gn] = acc[i][j];
        }
    }
}

// ---------------- attention logits: al_s[i,hd] = h[i,hd,:] . a_src[hd,:] ----------------

__global__ void row_alpha_kernel(const float* __restrict__ h, const float* __restrict__ a_src,
                                 const float* __restrict__ a_dst, float* __restrict__ al_s,
                                 float* __restrict__ al_d, int n, int heads, int ch) {
    int i = blockIdx.x * (blockDim.x >> 6) + (threadIdx.x >> 6);
    int lane = threadIdx.x & 63;
    if (i >= n) return;
    for (int hd = 0; hd < heads; hd++) {
        float ps = 0.f, pd = 0.f;
        for (int c = lane; c < ch; c += 64) {
            float v = h[(size_t)i * heads * ch + hd * ch + c];
            ps += v * a_src[hd * ch + c];
            pd += v * a_dst[hd * ch + c];
        }
        #pragma unroll
        for (int ofs = 32; ofs > 0; ofs >>= 1) {
            ps += __shfl_down(ps, ofs);
            pd += __shfl_down(pd, ofs);
        }
        if (lane == 0) {
            al_s[(size_t)i * heads + hd] = ps;
            al_d[(size_t)i * heads + hd] = pd;
        }
    }
}

// ---------------- concat aggregation (layers 1&2): wave per (node, head), ch=64 ----------------
// out[i, hd*64+lane] = ELU( sum_j alpha_ij * h[src_j, hd*64+lane] + bias + res )

__global__ void agg_concat_kernel(const float* __restrict__ h, const float* __restrict__ al_s,
                                  const float* __restrict__ al_d, const int* __restrict__ row_ptr,
                                  const int* __restrict__ csr_src, const float* __restrict__ res,
                                  const float* __restrict__ bias, float* __restrict__ out,
                                  int n, int heads) {
    int i = blockIdx.x;
    int hd = threadIdx.x >> 6;
    int lane = threadIdx.x & 63;
    if (hd >= heads) return;
    int beg = row_ptr[i], end = row_ptr[i + 1];
    float ald = al_d[(size_t)i * heads + hd];
    // phase 1: segment max
    float m = -1e30f;
    for (int j = beg + lane; j < end; j += 64) {
        int s = csr_src[j];
        float e = al_s[(size_t)s * heads + hd] + ald;
        e = e > 0.f ? e : 0.2f * e;
        m = fmaxf(m, e);
    }
    #pragma unroll
    for (int ofs = 32; ofs > 0; ofs >>= 1) m = fmaxf(m, __shfl_down(m, ofs));
    m = __shfl(m, 0);
    // phase 2: sum of exp
    float S = 0.f;
    for (int j = beg + lane; j < end; j += 64) {
        int s = csr_src[j];
        float e = al_s[(size_t)s * heads + hd] + ald;
        e = e > 0.f ? e : 0.2f * e;
        S += __expf(e - m);
    }
    #pragma unroll
    for (int ofs = 32; ofs > 0; ofs >>= 1) S += __shfl_down(S, ofs);
    S = __shfl(S, 0);
    float inv = 1.f / (S + 1e-16f);
    // phase 3: weighted accumulate (lane = channel)
    float acc = 0.f;
    for (int j = beg; j < end; j++) {
        int s = csr_src[j];  // broadcast
        float e = al_s[(size_t)s * heads + hd] + ald;
        e = e > 0.f ? e : 0.2f * e;
        float w = __expf(e - m) * inv;
        acc += w * h[(size_t)s * heads * 64 + hd * 64 + lane];
    }
    int col = hd * 64 + lane;
    float v = acc + bias[col];
    if (res) v += res[(size_t)i * heads * 64 + col];
    v = v > 0.f ? v : (__expf(v) - 1.f);  // ELU
    out[(size_t)i * heads * 64 + col] = v;
}

// ---------------- mean aggregation (layer 3): one block (128 thr) per node, per-head ----------------
// out[i,c] (+)= scale * sum_j alpha_ij * h[src_j, c]

__global__ void agg_mean_kernel(const float* __restrict__ h, const float* __restrict__ al_s,
                                const float* __restrict__ al_d, const int* __restrict__ row_ptr,
                                const int* __restrict__ csr_src, float* __restrict__ out,
                                int n, int ch, float scale, int add) {
    int i = blockIdx.x;
    int tid = threadIdx.x;
    __shared__ float sm, sinv;
    int beg = row_ptr[i], end = row_ptr[i + 1];
    float ald = al_d[i];
    if (tid < 64) {
        float m = -1e30f;
        for (int j = beg + tid; j < end; j += 64) {
            int s = csr_src[j];
            float e = al_s[s] + ald;
            e = e > 0.f ? e : 0.2f * e;
            m = fmaxf(m, e);
        }
        #pragma unroll
        for (int ofs = 32; ofs > 0; ofs >>= 1) m = fmaxf(m, __shfl_down(m, ofs));
        m = __shfl(m, 0);
        float S = 0.f;
        for (int j = beg + tid; j < end; j += 64) {
            int s = csr_src[j];
            float e = al_s[s] + ald;
            e = e > 0.f ? e : 0.2f * e;
            S += __expf(e - m);
        }
        #pragma unroll
        for (int ofs = 32; ofs > 0; ofs >>= 1) S += __shfl_down(S, ofs);
        if (tid == 0) { sm = m; sinv = 1.f / (S + 1e-16f); }
    }
    __syncthreads();
    float m = sm, inv = sinv;
    float acc = 0.f;
    int c = tid;
    for (int j = beg; j < end; j++) {
        int s = csr_src[j];
        float e = al_s[s] + ald;
        e = e > 0.f ? e : 0.2f * e;
        float w = __expf(e - m) * inv;
        if (c < ch) acc += w * h[(size_t)s * ch + c];
    }
    if (c < ch) {
        size_t o = (size_t)i * ch + c;
        if (add) out[o] += acc * scale;
        else out[o] = acc * scale;
    }
}

__global__ void bias_sigmoid_kernel(float* __restrict__ out, const float* __restrict__ b,
                                    int n, int ch) {
    int idx = blockIdx.x * blockDim.x + threadIdx.x;
    if (idx >= n * ch) return;
    int c = idx % ch;
    float v = out[idx] + b[c];
    out[idx] = 1.f / (1.f + __expf(-v));
}

// ---------------- host ----------------

extern "C" void kernel_launch(void* const* d_in, const int* in_sizes, int n_in,
                              void* d_out, int out_size, void* d_ws, size_t ws_size,
                              hipStream_t stream) {
    const float* x      = (const float*)d_in[0];
    const int*   src    = (const int*)d_in[1];
    const int*   dst    = (const int*)d_in[2];
    const float* W1     = (const float*)d_in[3];
    const float* a1_src = (const float*)d_in[4];
    const float* a1_dst = (const float*)d_in[5];
    const float* b1     = (const float*)d_in[6];
    const float* W2     = (const float*)d_in[7];
    const float* a2_src = (const float*)d_in[8];
    const float* a2_dst = (const float*)d_in[9];
    const float* b2     = (const float*)d_in[10];
    const float* Wres2  = (const float*)d_in[11];
    const float* W3     = (const float*)d_in[12];
    const float* a3_src = (const float*)d_in[13];
    const float* a3_dst = (const float*)d_in[14];
    const float* b3     = (const float*)d_in[15];
    float* out = (float*)d_out;

    const int N = NODES, E = EDGES;

    // workspace carve (aligned to 512B); total ~160 MB
    char* p = (char*)d_ws;
    auto alloc = [&](size_t bytes) -> char* {
        char* r = p;
        p += (bytes + 511) & ~(size_t)511;
        return r;
    };
    int*   row_ptr = (int*)alloc((size_t)(N + 1) * sizeof(int));
    int*   cursor  = (int*)alloc((size_t)N * sizeof(int));
    int*   deg     = (int*)alloc((size_t)N * sizeof(int));
    int*   csr_src = (int*)alloc((size_t)(E + N) * sizeof(int));
    float* al_s    = (float*)alloc((size_t)N * 6 * sizeof(float));
    float* al_d    = (float*)alloc((size_t)N * 6 * sizeof(float));
    float* hA      = (float*)alloc((size_t)N * 256 * sizeof(float));  // h1 / h2
    float* hB      = (float*)alloc((size_t)N * 256 * sizeof(float));  // out1 / out2
    float* hC      = (float*)alloc((size_t)N * 256 * sizeof(float));  // res2 / h3-head
    (void)ws_size; (void)n_in; (void)in_sizes; (void)out_size;

    // --- CSR build (dst-sorted adjacency incl. self-loops) ---
    fill_ones_kernel<<<(N + 255) / 256, 256, 0, stream>>>(deg, N);
    hist_kernel<<<(E + 255) / 256, 256, 0, stream>>>(dst, deg, E);
    scan_kernel<<<1, 1024, 0, stream>>>(deg, row_ptr, cursor, N);
    scatter_kernel<<<(E + N + 255) / 256, 256, 0, stream>>>(src, dst, E, N, cursor, csr_src);

    dim3 g256((N + BM - 1) / BM, 4);
    dim3 g121((N + BM - 1) / BM, 2);

    // --- layer 1: IN=128 -> 4 heads x 64, concat, ELU ---
    gemm_kernel<<<g256, 256, 0, stream>>>(x, W1, hA, N, 256, 128, 256, 256);
    row_alpha_kernel<<<(N + 3) / 4, 256, 0, stream>>>(hA, a1_src, a1_dst, al_s, al_d, N, 4, 64);
    agg_concat_kernel<<<N, 256, 0, stream>>>(hA, al_s, al_d, row_ptr, csr_src,
                                             nullptr, b1, hB, N, 4);

    // --- layer 2: 256 -> 4 heads x 64, concat, residual, ELU ---
    gemm_kernel<<<g256, 256, 0, stream>>>(hB, W2, hA, N, 256, 256, 256, 256);
    gemm_kernel<<<g256, 256, 0, stream>>>(hB, Wres2, hC, N, 256, 256, 256, 256);
    row_alpha_kernel<<<(N + 3) / 4, 256, 0, stream>>>(hA, a2_src, a2_dst, al_s, al_d, N, 4, 64);
    agg_concat_kernel<<<N, 256, 0, stream>>>(hA, al_s, al_d, row_ptr, csr_src,
                                             hC, b2, hB, N, 4);

    // --- layer 3: 256 -> 6 heads x 121, mean over heads, sigmoid; head-chunked ---
    for (int hd = 0; hd < 6; hd++) {
        gemm_kernel<<<g121, 256, 0, stream>>>(hB, W3 + hd * 121, hC, N, 121, 256, 726, 121);
        row_alpha_kernel<<<(N + 3) / 4, 256, 0, stream>>>(hC, a3_src + hd * 121,
                                                          a3_dst + hd * 121, al_s, al_d, N, 1, 121);
        agg_mean_kernel<<<N, 128, 0, stream>>>(hC, al_s, al_d, row_ptr, csr_src,
                                               out, N, 121, 1.0f / 6.0f, hd > 0 ? 1 : 0);
    }
    bias_sigmoid_kernel<<<((N * 121) + 255) / 256, 256, 0, stream>>>(out, b3, N, 121);
}

// Round 2
// 1376.967 us; speedup vs baseline: 1.8440x; 1.8440x over previous
//
#include <hip/hip_runtime.h>
#include <hip/hip_bf16.h>

// PPI GAT, 3 layers. N=50000 nodes, E=800000 edges (+N self loops).
// R2: split-bf16 MFMA GEMMs (fp32-accurate), precomputed softmax weights,
//     gather-FMA aggregation, bf16 h3 for layer-3 gathers.

#define NODES 50000
#define EDGES 800000

typedef unsigned short u16;
typedef __attribute__((ext_vector_type(8))) short bf16x8;
typedef __attribute__((ext_vector_type(4))) float f32x4;

__device__ __forceinline__ float bf16f(u16 r) {
    return __uint_as_float(((unsigned)r) << 16);
}

// ---------------- CSR build ----------------

__global__ void fill_ones_kernel(int* __restrict__ deg, int n) {
    int i = blockIdx.x * blockDim.x + threadIdx.x;
    if (i < n) deg[i] = 1;  // self-loop
}

__global__ void hist_kernel(const int* __restrict__ dst, int* __restrict__ deg, int E) {
    int e = blockIdx.x * blockDim.x + threadIdx.x;
    if (e < E) atomicAdd(&deg[dst[e]], 1);
}

__global__ void scan_kernel(const int* __restrict__ deg, int* __restrict__ row_ptr,
                            int* __restrict__ cursor, int n) {
    __shared__ int s_ws[16];
    __shared__ int s_off;
    __shared__ int s_total;
    int tid = threadIdx.x, lane = tid & 63, wid = tid >> 6;
    if (tid == 0) s_off = 0;
    __syncthreads();
    for (int base = 0; base < n; base += 1024) {
        int i = base + tid;
        int v = (i < n) ? deg[i] : 0;
        int incl = v;
        #pragma unroll
        for (int ofs = 1; ofs < 64; ofs <<= 1) {
            int t = __shfl_up(incl, ofs);
            if (lane >= ofs) incl += t;
        }
        if (lane == 63) s_ws[wid] = incl;
        __syncthreads();
        if (tid == 0) {
            int run = 0;
            for (int k = 0; k < 16; k++) { int t = s_ws[k]; s_ws[k] = run; run += t; }
            s_total = run;
        }
        __syncthreads();
        int excl = incl - v + s_ws[wid] + s_off;
        if (i < n) { row_ptr[i] = excl; cursor[i] = excl; }
        __syncthreads();
        if (tid == 0) s_off += s_total;
        __syncthreads();
    }
    if (tid == 0) row_ptr[n] = s_off;
}

__global__ void scatter_kernel(const int* __restrict__ src, const int* __restrict__ dst,
                               int E, int n, int* __restrict__ cursor, int* __restrict__ csr_src) {
    int e = blockIdx.x * blockDim.x + threadIdx.x;
    if (e < E) {
        int d = dst[e];
        int p = atomicAdd(&cursor[d], 1);
        csr_src[p] = src[e];
    } else if (e < E + n) {
        int i = e - E;
        int p = atomicAdd(&cursor[i], 1);
        csr_src[p] = i;  // self-loop
    }
}

// ---------------- fp32 -> split bf16 (hi,lo interleaved along K) ----------------
// A fp32 [M,K] -> A2 bf16 [M, 2K]:  A2[m,2k]=hi, A2[m,2k+1]=lo; hi+lo ~= A to 2^-17 rel.

__global__ void convertA_kernel(const float* __restrict__ A, u16* __restrict__ A2,
                                int M, int K) {
    int idx = blockIdx.x * blockDim.x + threadIdx.x;
    if (idx >= M * K) return;
    float f = A[idx];
    __hip_bfloat16 h = __float2bfloat16(f);
    float fh = __bfloat162float(h);
    __hip_bfloat16 l = __float2bfloat16(f - fh);
    ushort2 p;
    p.x = *(u16*)&h;
    p.y = *(u16*)&l;
    ((ushort2*)A2)[idx] = p;  // row stride 2K ushorts == K ushort2
}

// W fp32 [K, ldw] (cols col0..col0+Ncols) -> WT2 bf16 [Npad, 2K] transposed:
// WT2[n, 2k]=hi(W[k, col0+n]), WT2[n, 2k+1]=lo. Zero-filled for n>=Ncols.

__global__ void convertW_kernel(const float* __restrict__ W, int ldw, int col0,
                                int Ncols, int Npad, int K, u16* __restrict__ WT2) {
    int idx = blockIdx.x * blockDim.x + threadIdx.x;
    if (idx >= Npad * K) return;
    int k = idx % K;
    int n = idx / K;
    float f = (n < Ncols) ? W[(size_t)k * ldw + col0 + n] : 0.f;
    __hip_bfloat16 h = __float2bfloat16(f);
    float fh = __bfloat162float(h);
    __hip_bfloat16 l = __float2bfloat16(f - fh);
    ushort2 p;
    p.x = *(u16*)&h;
    p.y = *(u16*)&l;
    ((ushort2*)WT2)[(size_t)n * K + k] = p;
}

// ---------------- bf16 MFMA GEMM: C[M,Ncols] = A2[M,K2] @ WT2[Npad,K2]^T ----------------
// 128x128 block tile, 4 waves (2x2), each wave 64x64 = 4x4 MFMA 16x16x32 tiles.
// A2 must be allocated with ceil(M/128)*128 rows (garbage rows OK; stores guarded).

__global__ __launch_bounds__(256) void gemm_mfma_kernel(
    const u16* __restrict__ A2, const u16* __restrict__ WT2,
    float* __restrict__ Cf, u16* __restrict__ Cb,
    int M, int Ncols, int K2, int ldc) {
    __shared__ __align__(16) u16 As[128][40];
    __shared__ __align__(16) u16 Bs[128][40];
    int tid = threadIdx.x;
    int lane = tid & 63;
    int wv = tid >> 6;
    int quad = lane >> 4, lm = lane & 15;
    int wm = (wv & 1) * 64, wn = (wv >> 1) * 64;
    int bm = blockIdx.x * 128, bn = blockIdx.y * 128;

    f32x4 zero = {0.f, 0.f, 0.f, 0.f};
    f32x4 acc[4][4];
    #pragma unroll
    for (int i = 0; i < 4; i++)
        #pragma unroll
        for (int j = 0; j < 4; j++) acc[i][j] = zero;

    for (int k0 = 0; k0 < K2; k0 += 32) {
        #pragma unroll
        for (int it = 0; it < 2; ++it) {
            int chunk = tid + it * 256;
            int row = chunk >> 2, seg = chunk & 3;
            uint4 va = *(const uint4*)(A2 + (size_t)(bm + row) * K2 + k0 + seg * 8);
            uint4 vb = *(const uint4*)(WT2 + (size_t)(bn + row) * K2 + k0 + seg * 8);
            *(uint4*)&As[row][seg * 8] = va;
            *(uint4*)&Bs[row][seg * 8] = vb;
        }
        __syncthreads();
        bf16x8 af[4], bfr[4];
        #pragma unroll
        for (int i = 0; i < 4; i++) af[i] = *(const bf16x8*)&As[wm + i * 16 + lm][quad * 8];
        #pragma unroll
        for (int j = 0; j < 4; j++) bfr[j] = *(const bf16x8*)&Bs[wn + j * 16 + lm][quad * 8];
        #pragma unroll
        for (int i = 0; i < 4; i++)
            #pragma unroll
            for (int j = 0; j < 4; j++)
                acc[i][j] = __builtin_amdgcn_mfma_f32_16x16x32_bf16(af[i], bfr[j], acc[i][j], 0, 0, 0);
        __syncthreads();
    }

    // C/D layout: col = lane&15, row = quad*4 + reg
    #pragma unroll
    for (int i = 0; i < 4; i++) {
        #pragma unroll
        for (int j = 0; j < 4; j++) {
            int col = bn + wn + j * 16 + lm;
            if (col >= Ncols) continue;
            int row_base = bm + wm + i * 16 + quad * 4;
            #pragma unroll
            for (int r = 0; r < 4; r++) {
                int row = row_base + r;
                if (row >= M) continue;
                float v = acc[i][j][r];
                if (Cf) {
                    Cf[(size_t)row * ldc + col] = v;
                } else {
                    __hip_bfloat16 b = __float2bfloat16(v);
                    Cb[(size_t)row * ldc + col] = *(u16*)&b;
                }
            }
        }
    }
}

// ---------------- attention logits ----------------

__global__ void row_alpha_kernel(const float* __restrict__ h, const float* __restrict__ a_src,
                                 const float* __restrict__ a_dst, float* __restrict__ al_s,
                                 float* __restrict__ al_d, int n, int heads, int ch) {
    int i = blockIdx.x * (blockDim.x >> 6) + (threadIdx.x >> 6);
    int lane = threadIdx.x & 63;
    if (i >= n) return;
    for (int hd = 0; hd < heads; hd++) {
        float ps = 0.f, pd = 0.f;
        for (int c = lane; c < ch; c += 64) {
            float v = h[(size_t)i * heads * ch + hd * ch + c];
            ps += v * a_src[hd * ch + c];
            pd += v * a_dst[hd * ch + c];
        }
        #pragma unroll
        for (int ofs = 32; ofs > 0; ofs >>= 1) {
            ps += __shfl_down(ps, ofs);
            pd += __shfl_down(pd, ofs);
        }
        if (lane == 0) {
            al_s[(size_t)i * heads + hd] = ps;
            al_d[(size_t)i * heads + hd] = pd;
        }
    }
}

// layer-3 (per head): h3 bf16 [N,128], ch=121
__global__ void row_alpha3_kernel(const u16* __restrict__ h3, const float* __restrict__ a_src,
                                  const float* __restrict__ a_dst, float* __restrict__ al_s,
                                  float* __restrict__ al_d, int n) {
    int i = blockIdx.x * 4 + (threadIdx.x >> 6);
    int lane = threadIdx.x & 63;
    if (i >= n) return;
    float ps = 0.f, pd = 0.f;
    for (int c = lane; c < 121; c += 64) {
        float v = bf16f(h3[(size_t)i * 128 + c]);
        ps += v * a_src[c];
        pd += v * a_dst[c];
    }
    #pragma unroll
    for (int ofs = 32; ofs > 0; ofs >>= 1) {
        ps += __shfl_down(ps, ofs);
        pd += __shfl_down(pd, ofs);
    }
    if (lane == 0) {
        al_s[i] = ps;
        al_d[i] = pd;
    }
}

// ---------------- softmax weights, 4 heads: wave per node, lanes over (edge,head) ----------------
// w4[e*4+h] = exp(leaky(al_s[src]+al_d[i]) - m) / S

__global__ void softmax4_kernel(const float* __restrict__ al_s, const float* __restrict__ al_d,
                                const int* __restrict__ row_ptr, const int* __restrict__ csr_src,
                                float* __restrict__ w4, int n) {
    int i = blockIdx.x * 4 + (threadIdx.x >> 6);
    int lane = threadIdx.x & 63;
    if (i >= n) return;
    int beg = row_ptr[i], end = row_ptr[i + 1];
    int h = lane & 3;
    int eo = lane >> 2;  // edge offset within 16-edge chunk
    float ald = al_d[(size_t)i * 4 + h];
    float m = -1e30f;
    for (int base = beg; base < end; base += 16) {
        int e = base + eo;
        if (e < end) {
            float v = al_s[(size_t)csr_src[e] * 4 + h] + ald;
            v = v > 0.f ? v : 0.2f * v;
            m = fmaxf(m, v);
        }
    }
    #pragma unroll
    for (int ofs = 4; ofs <= 32; ofs <<= 1) m = fmaxf(m, __shfl_xor(m, ofs));
    float S = 0.f;
    for (int base = beg; base < end; base += 16) {
        int e = base + eo;
        if (e < end) {
            float v = al_s[(size_t)csr_src[e] * 4 + h] + ald;
            v = v > 0.f ? v : 0.2f * v;
            S += __expf(v - m);
        }
    }
    #pragma unroll
    for (int ofs = 4; ofs <= 32; ofs <<= 1) S += __shfl_xor(S, ofs);
    float inv = 1.f / (S + 1e-16f);
    for (int base = beg; base < end; base += 16) {
        int e = base + eo;
        if (e < end) {
            float v = al_s[(size_t)csr_src[e] * 4 + h] + ald;
            v = v > 0.f ? v : 0.2f * v;
            w4[(size_t)e * 4 + h] = __expf(v - m) * inv;
        }
    }
}

// single-head variant (layer 3)
__global__ void softmax1_kernel(const float* __restrict__ al_s, const float* __restrict__ al_d,
                                const int* __restrict__ row_ptr, const int* __restrict__ csr_src,
                                float* __restrict__ w1, int n) {
    int i = blockIdx.x * 4 + (threadIdx.x >> 6);
    int lane = threadIdx.x & 63;
    if (i >= n) return;
    int beg = row_ptr[i], end = row_ptr[i + 1];
    float ald = al_d[i];
    float m = -1e30f;
    for (int e = beg + lane; e < end; e += 64) {
        float v = al_s[csr_src[e]] + ald;
        v = v > 0.f ? v : 0.2f * v;
        m = fmaxf(m, v);
    }
    #pragma unroll
    for (int ofs = 1; ofs <= 32; ofs <<= 1) m = fmaxf(m, __shfl_xor(m, ofs));
    float S = 0.f;
    for (int e = beg + lane; e < end; e += 64) {
        float v = al_s[csr_src[e]] + ald;
        v = v > 0.f ? v : 0.2f * v;
        S += __expf(v - m);
    }
    #pragma unroll
    for (int ofs = 1; ofs <= 32; ofs <<= 1) S += __shfl_xor(S, ofs);
    float inv = 1.f / (S + 1e-16f);
    for (int e = beg + lane; e < end; e += 64) {
        float v = al_s[csr_src[e]] + ald;
        v = v > 0.f ? v : 0.2f * v;
        w1[e] = __expf(v - m) * inv;
    }
}

// ---------------- aggregation, layers 1&2: block(256) per node, pure gather-FMA ----------------

__global__ __launch_bounds__(256) void agg_concat_kernel(
    const float* __restrict__ f, const float* __restrict__ w4,
    const int* __restrict__ row_ptr, const int* __restrict__ csr_src,
    const float* __restrict__ bias, float* __restrict__ out, int use_res) {
    __shared__ int s_idx[64];
    __shared__ float s_w[64][4];
    int i = blockIdx.x;
    int tid = threadIdx.x;
    int hd = tid >> 6;
    int beg = row_ptr[i], end = row_ptr[i + 1];
    float acc = 0.f;
    for (int base = beg; base < end; base += 64) {
        int cnt = min(64, end - base);
        __syncthreads();
        if (tid < cnt) {
            int e = base + tid;
            s_idx[tid] = csr_src[e];
            float4 ww = ((const float4*)w4)[e];
            s_w[tid][0] = ww.x; s_w[tid][1] = ww.y; s_w[tid][2] = ww.z; s_w[tid][3] = ww.w;
        }
        __syncthreads();
        int c = 0;
        for (; c + 4 <= cnt; c += 4) {
            int s0 = s_idx[c], s1 = s_idx[c + 1], s2 = s_idx[c + 2], s3 = s_idx[c + 3];
            float w0 = s_w[c][hd], w1 = s_w[c + 1][hd], w2 = s_w[c + 2][hd], w3 = s_w[c + 3][hd];
            float v0 = f[(size_t)s0 * 256 + tid];
            float v1 = f[(size_t)s1 * 256 + tid];
            float v2 = f[(size_t)s2 * 256 + tid];
            float v3 = f[(size_t)s3 * 256 + tid];
            acc += w0 * v0; acc += w1 * v1; acc += w2 * v2; acc += w3 * v3;
        }
        for (; c < cnt; c++) acc += s_w[c][hd] * f[(size_t)s_idx[c] * 256 + tid];
    }
    size_t o = (size_t)i * 256 + tid;
    float v = acc + bias[tid];
    if (use_res) v += out[o];
    v = v > 0.f ? v : (__expf(v) - 1.f);  // ELU
    out[o] = v;
}

// ---------------- aggregation, layer 3 per head: bf16 gather, RMW into out ----------------

__global__ __launch_bounds__(128) void agg_mean3_kernel(
    const u16* __restrict__ h3, const float* __restrict__ w1,
    const int* __restrict__ row_ptr, const int* __restrict__ csr_src,
    float* __restrict__ out, int first) {
    __shared__ int s_idx[64];
    __shared__ float s_w[64];
    int i = blockIdx.x;
    int tid = threadIdx.x;
    int beg = row_ptr[i], end = row_ptr[i + 1];
    float acc = 0.f;
    for (int base = beg; base < end; base += 64) {
        int cnt = min(64, end - base);
        __syncthreads();
        if (tid < cnt) {
            s_idx[tid] = csr_src[base + tid];
            s_w[tid] = w1[base + tid];
        }
        __syncthreads();
        if (tid < 121) {
            int c = 0;
            for (; c + 4 <= cnt; c += 4) {
                float v0 = bf16f(h3[(size_t)s_idx[c] * 128 + tid]);
                float v1 = bf16f(h3[(size_t)s_idx[c + 1] * 128 + tid]);
                float v2 = bf16f(h3[(size_t)s_idx[c + 2] * 128 + tid]);
                float v3 = bf16f(h3[(size_t)s_idx[c + 3] * 128 + tid]);
                acc += s_w[c] * v0; acc += s_w[c + 1] * v1;
                acc += s_w[c + 2] * v2; acc += s_w[c + 3] * v3;
            }
            for (; c < cnt; c++) acc += s_w[c] * bf16f(h3[(size_t)s_idx[c] * 128 + tid]);
        }
    }
    if (tid < 121) {
        size_t o = (size_t)i * 121 + tid;
        float v = acc * (1.f / 6.f);
        out[o] = first ? v : out[o] + v;
    }
}

__global__ void bias_sigmoid_kernel(float* __restrict__ out, const float* __restrict__ b,
                                    int n, int ch) {
    int idx = blockIdx.x * blockDim.x + threadIdx.x;
    if (idx >= n * ch) return;
    int c = idx % ch;
    float v = out[idx] + b[c];
    out[idx] = 1.f / (1.f + __expf(-v));
}

// ---------------- host ----------------

extern "C" void kernel_launch(void* const* d_in, const int* in_sizes, int n_in,
                              void* d_out, int out_size, void* d_ws, size_t ws_size,
                              hipStream_t stream) {
    const float* x      = (const float*)d_in[0];
    const int*   src    = (const int*)d_in[1];
    const int*   dst    = (const int*)d_in[2];
    const float* W1     = (const float*)d_in[3];
    const float* a1_src = (const float*)d_in[4];
    const float* a1_dst = (const float*)d_in[5];
    const float* b1     = (const float*)d_in[6];
    const float* W2     = (const float*)d_in[7];
    const float* a2_src = (const float*)d_in[8];
    const float* a2_dst = (const float*)d_in[9];
    const float* b2     = (const float*)d_in[10];
    const float* Wres2  = (const float*)d_in[11];
    const float* W3     = (const float*)d_in[12];
    const float* a3_src = (const float*)d_in[13];
    const float* a3_dst = (const float*)d_in[14];
    const float* b3     = (const float*)d_in[15];
    float* out = (float*)d_out;

    const int N = NODES, E = EDGES;
    const int EN = E + N;
    const int Mpad = 50048;  // ceil(N/128)*128

    char* p = (char*)d_ws;
    auto alloc = [&](size_t bytes) -> char* {
        char* r = p;
        p += (bytes + 511) & ~(size_t)511;
        return r;
    };
    int*   row_ptr = (int*)alloc((size_t)(N + 1) * sizeof(int));
    int*   cursor  = (int*)alloc((size_t)N * sizeof(int));
    int*   deg     = (int*)alloc((size_t)N * sizeof(int));
    int*   csr_src = (int*)alloc((size_t)EN * sizeof(int));
    float* al_s    = (float*)alloc((size_t)N * 4 * sizeof(float));
    float* al_d    = (float*)alloc((size_t)N * 4 * sizeof(float));
    float* w4      = (float*)alloc((size_t)EN * 4 * sizeof(float));  // also w1 plane
    u16*   A2      = (u16*)alloc((size_t)Mpad * 512 * sizeof(u16));
    u16*   WT2     = (u16*)alloc((size_t)256 * 1024 * sizeof(u16));
    float* f1      = (float*)alloc((size_t)N * 256 * sizeof(float));  // h (gather src)
    float* o1      = (float*)alloc((size_t)N * 256 * sizeof(float));  // layer output / res
    u16*   h3c     = (u16*)alloc((size_t)N * 128 * sizeof(u16));      // bf16 per-head h3
    (void)ws_size; (void)n_in; (void)in_sizes; (void)out_size;

    // --- CSR build ---
    fill_ones_kernel<<<(N + 255) / 256, 256, 0, stream>>>(deg, N);
    hist_kernel<<<(E + 255) / 256, 256, 0, stream>>>(dst, deg, E);
    scan_kernel<<<1, 1024, 0, stream>>>(deg, row_ptr, cursor, N);
    scatter_kernel<<<(E + N + 255) / 256, 256, 0, stream>>>(src, dst, E, N, cursor, csr_src);

    int nwb = (N + 3) / 4;  // wave-per-node grids

    // --- layer 1: 128 -> 4x64 concat, ELU ---
    convertA_kernel<<<(N * 128 + 255) / 256, 256, 0, stream>>>(x, A2, N, 128);
    convertW_kernel<<<(256 * 128 + 255) / 256, 256, 0, stream>>>(W1, 256, 0, 256, 256, 128, WT2);
    {
        dim3 g(Mpad / 128, 2);
        gemm_mfma_kernel<<<g, 256, 0, stream>>>(A2, WT2, f1, nullptr, N, 256, 256, 256);
    }
    row_alpha_kernel<<<nwb, 256, 0, stream>>>(f1, a1_src, a1_dst, al_s, al_d, N, 4, 64);
    softmax4_kernel<<<nwb, 256, 0, stream>>>(al_s, al_d, row_ptr, csr_src, w4, N);
    agg_concat_kernel<<<N, 256, 0, stream>>>(f1, w4, row_ptr, csr_src, b1, o1, 0);

    // --- layer 2: 256 -> 4x64 concat + residual, ELU ---
    convertA_kernel<<<(N * 256 + 255) / 256, 256, 0, stream>>>(o1, A2, N, 256);
    convertW_kernel<<<(256 * 256 + 255) / 256, 256, 0, stream>>>(W2, 256, 0, 256, 256, 256, WT2);
    {
        dim3 g(Mpad / 128, 2);
        gemm_mfma_kernel<<<g, 256, 0, stream>>>(A2, WT2, f1, nullptr, N, 256, 512, 256);
    }
    convertW_kernel<<<(256 * 256 + 255) / 256, 256, 0, stream>>>(Wres2, 256, 0, 256, 256, 256, WT2);
    {
        dim3 g(Mpad / 128, 2);
        gemm_mfma_kernel<<<g, 256, 0, stream>>>(A2, WT2, o1, nullptr, N, 256, 512, 256);  // res -> o1
    }
    row_alpha_kernel<<<nwb, 256, 0, stream>>>(f1, a2_src, a2_dst, al_s, al_d, N, 4, 64);
    softmax4_kernel<<<nwb, 256, 0, stream>>>(al_s, al_d, row_ptr, csr_src, w4, N);
    agg_concat_kernel<<<N, 256, 0, stream>>>(f1, w4, row_ptr, csr_src, b2, o1, 1);

    // --- layer 3: 256 -> 6 heads x 121, mean, sigmoid; per-head ---
    convertA_kernel<<<(N * 256 + 255) / 256, 256, 0, stream>>>(o1, A2, N, 256);
    for (int hd = 0; hd < 6; hd++) {
        convertW_kernel<<<(128 * 256 + 255) / 256, 256, 0, stream>>>(
            W3, 726, hd * 121, 121, 128, 256, WT2);
        {
            dim3 g(Mpad / 128, 1);
            gemm_mfma_kernel<<<g, 256, 0, stream>>>(A2, WT2, nullptr, h3c, N, 121, 512, 128);
        }
        row_alpha3_kernel<<<nwb, 256, 0, stream>>>(h3c, a3_src + hd * 121, a3_dst + hd * 121,
                                                   al_s, al_d, N);
        softmax1_kernel<<<nwb, 256, 0, stream>>>(al_s, al_d, row_ptr, csr_src, w4, N);
        agg_mean3_kernel<<<N, 128, 0, stream>>>(h3c, w4, row_ptr, csr_src, out, hd == 0 ? 1 : 0);
    }
    bias_sigmoid_kernel<<<((N * 121) + 255) / 256, 256, 0, stream>>>(out, b3, N, 121);
}

// Round 3
// 894.003 us; speedup vs baseline: 2.8401x; 1.5402x over previous
//
#include <hip/hip_runtime.h>
#include <hip/hip_bf16.h>

// PPI GAT, 3 layers. N=50000, E=800000 (+N self loops).
// R3: all-plain-bf16 MFMA GEMMs (R2's "split" was only bf16-accurate anyway),
//     bf16 gathers everywhere, layer-3 aggregation in input space:
//     S[i,h*256+k] = sum_j w_jh x_j[k];  out = sigmoid((1/6) S @ W3stack + b3).

#define NODES 50000
#define EDGES 800000
#define MPAD  50048            // ceil(N/128)*128
#define C0    25088            // chunk-0 rows (196 tiles)
#define C1R   24960            // chunk-1 padded rows (195 tiles)

typedef unsigned short u16;
typedef __attribute__((ext_vector_type(8))) short bf16x8;
typedef __attribute__((ext_vector_type(4))) float f32x4;

__device__ __forceinline__ float bf16f(u16 r) {
    return __uint_as_float(((unsigned)r) << 16);
}
__device__ __forceinline__ u16 f2b(float v) {
    __hip_bfloat16 b = __float2bfloat16(v);
    return *(u16*)&b;
}

// ---------------- CSR build ----------------

__global__ void fill_ones_kernel(int* __restrict__ deg, int n) {
    int i = blockIdx.x * blockDim.x + threadIdx.x;
    if (i < n) deg[i] = 1;  // self-loop
}

__global__ void hist_kernel(const int* __restrict__ dst, int* __restrict__ deg, int E) {
    int e = blockIdx.x * blockDim.x + threadIdx.x;
    if (e < E) atomicAdd(&deg[dst[e]], 1);
}

__global__ void scan_kernel(const int* __restrict__ deg, int* __restrict__ row_ptr,
                            int* __restrict__ cursor, int n) {
    __shared__ int s_ws[16];
    __shared__ int s_off;
    __shared__ int s_total;
    int tid = threadIdx.x, lane = tid & 63, wid = tid >> 6;
    if (tid == 0) s_off = 0;
    __syncthreads();
    for (int base = 0; base < n; base += 1024) {
        int i = base + tid;
        int v = (i < n) ? deg[i] : 0;
        int incl = v;
        #pragma unroll
        for (int ofs = 1; ofs < 64; ofs <<= 1) {
            int t = __shfl_up(incl, ofs);
            if (lane >= ofs) incl += t;
        }
        if (lane == 63) s_ws[wid] = incl;
        __syncthreads();
        if (tid == 0) {
            int run = 0;
            for (int k = 0; k < 16; k++) { int t = s_ws[k]; s_ws[k] = run; run += t; }
            s_total = run;
        }
        __syncthreads();
        int excl = incl - v + s_ws[wid] + s_off;
        if (i < n) { row_ptr[i] = excl; cursor[i] = excl; }
        __syncthreads();
        if (tid == 0) s_off += s_total;
        __syncthreads();
    }
    if (tid == 0) row_ptr[n] = s_off;
}

__global__ void scatter_kernel(const int* __restrict__ src, const int* __restrict__ dst,
                               int E, int n, int* __restrict__ cursor, int* __restrict__ csr_src) {
    int e = blockIdx.x * blockDim.x + threadIdx.x;
    if (e < E) {
        int d = dst[e];
        int p = atomicAdd(&cursor[d], 1);
        csr_src[p] = src[e];
    } else if (e < E + n) {
        int i = e - E;
        int p = atomicAdd(&cursor[i], 1);
        csr_src[p] = i;  // self-loop
    }
}

// ---------------- converts ----------------

__global__ void convertA4_kernel(const float* __restrict__ A, u16* __restrict__ O, int total4) {
    int idx = blockIdx.x * blockDim.x + threadIdx.x;
    if (idx >= total4) return;
    float4 f = ((const float4*)A)[idx];
    ushort4 o;
    o.x = f2b(f.x); o.y = f2b(f.y); o.z = f2b(f.z); o.w = f2b(f.w);
    ((ushort4*)O)[idx] = o;
}

// W fp32 [K, ldw] cols col0..col0+Ncols -> WT bf16 [Npad, K]; zero pad rows.
__global__ void convertW_kernel(const float* __restrict__ W, int ldw, int col0,
                                int Ncols, int Npad, int K, u16* __restrict__ WT) {
    int idx = blockIdx.x * blockDim.x + threadIdx.x;
    if (idx >= Npad * K) return;
    int k = idx % K;
    int n = idx / K;
    float f = (n < Ncols) ? W[(size_t)k * ldw + col0 + n] : 0.f;
    WT[(size_t)n * K + k] = f2b(f);
}

// W3stackT[n, h*256+k] = W3[k, h*121+n]  (n<121 else 0), bf16 [128, 1536]
__global__ void convertW3stack_kernel(const float* __restrict__ W3, u16* __restrict__ WT) {
    int idx = blockIdx.x * blockDim.x + threadIdx.x;
    if (idx >= 128 * 1536) return;
    int q = idx % 1536;
    int n = idx / 1536;
    int h = q >> 8, k = q & 255;
    float f = (n < 121) ? W3[(size_t)k * 726 + h * 121 + n] : 0.f;
    WT[(size_t)n * 1536 + q] = f2b(f);
}

// cmT[o, k] = sum_c W3[k, h*121+c] * a3[h,c];  o<6: a3_src(h=o), o<12: a3_dst(h=o-6); else 0.
__global__ void prep_cmat_kernel(const float* __restrict__ W3, const float* __restrict__ a3s,
                                 const float* __restrict__ a3d, u16* __restrict__ cmT) {
    int idx = blockIdx.x * blockDim.x + threadIdx.x;
    if (idx >= 128 * 256) return;
    int k = idx & 255;
    int o = idx >> 8;
    float v = 0.f;
    if (o < 12) {
        int h = o % 6;
        const float* a = (o < 6) ? a3s : a3d;
        for (int c = 0; c < 121; c++) v += W3[(size_t)k * 726 + h * 121 + c] * a[h * 121 + c];
    }
    cmT[(size_t)o * 256 + k] = f2b(v);
}

// ---------------- bf16 MFMA GEMM: C[M,Ncols] = A[M,K2] @ WT[Npad,K2]^T ----------------
// 128x128 tile, 4 waves 2x2, 16x16x32 MFMA. act=1: v = sigmoid(v + bias[col]).

__global__ __launch_bounds__(256) void gemm_mfma_kernel(
    const u16* __restrict__ A, const u16* __restrict__ B,
    float* __restrict__ Cf, u16* __restrict__ Cb,
    int M, int Ncols, int K2, int ldc,
    const float* __restrict__ bias, int act) {
    __shared__ __align__(16) u16 As[128][40];
    __shared__ __align__(16) u16 Bs[128][40];
    int tid = threadIdx.x;
    int lane = tid & 63;
    int wv = tid >> 6;
    int quad = lane >> 4, lm = lane & 15;
    int wm = (wv & 1) * 64, wn = (wv >> 1) * 64;
    int bm = blockIdx.x * 128, bn = blockIdx.y * 128;

    f32x4 zero = {0.f, 0.f, 0.f, 0.f};
    f32x4 acc[4][4];
    #pragma unroll
    for (int i = 0; i < 4; i++)
        #pragma unroll
        for (int j = 0; j < 4; j++) acc[i][j] = zero;

    for (int k0 = 0; k0 < K2; k0 += 32) {
        #pragma unroll
        for (int it = 0; it < 2; ++it) {
            int chunk = tid + it * 256;
            int row = chunk >> 2, seg = chunk & 3;
            uint4 va = *(const uint4*)(A + (size_t)(bm + row) * K2 + k0 + seg * 8);
            uint4 vb = *(const uint4*)(B + (size_t)(bn + row) * K2 + k0 + seg * 8);
            *(uint4*)&As[row][seg * 8] = va;
            *(uint4*)&Bs[row][seg * 8] = vb;
        }
        __syncthreads();
        bf16x8 af[4], bfr[4];
        #pragma unroll
        for (int i = 0; i < 4; i++) af[i] = *(const bf16x8*)&As[wm + i * 16 + lm][quad * 8];
        #pragma unroll
        for (int j = 0; j < 4; j++) bfr[j] = *(const bf16x8*)&Bs[wn + j * 16 + lm][quad * 8];
        #pragma unroll
        for (int i = 0; i < 4; i++)
            #pragma unroll
            for (int j = 0; j < 4; j++)
                acc[i][j] = __builtin_amdgcn_mfma_f32_16x16x32_bf16(af[i], bfr[j], acc[i][j], 0, 0, 0);
        __syncthreads();
    }

    // C/D layout: col = lane&15, row = quad*4 + reg
    #pragma unroll
    for (int i = 0; i < 4; i++) {
        #pragma unroll
        for (int j = 0; j < 4; j++) {
            int col = bn + wn + j * 16 + lm;
            if (col >= Ncols) continue;
            int row_base = bm + wm + i * 16 + quad * 4;
            #pragma unroll
            for (int r = 0; r < 4; r++) {
                int row = row_base + r;
                if (row >= M) continue;
                float v = acc[i][j][r];
                if (act == 1) {
                    v += bias[col];
                    v = 1.f / (1.f + __expf(-v));
                }
                if (Cf) Cf[(size_t)row * ldc + col] = v;
                else    Cb[(size_t)row * ldc + col] = f2b(v);
            }
        }
    }
}

// ---------------- attention logits, layers 1&2 (4 heads x 64ch, bf16 h) ----------------

__global__ void row_alpha4_kernel(const u16* __restrict__ f, const float* __restrict__ a_s,
                                  const float* __restrict__ a_d, float* __restrict__ al_s,
                                  float* __restrict__ al_d, int n) {
    int wv = threadIdx.x >> 6, lane = threadIdx.x & 63;
    int i = blockIdx.x * 4 + wv;
    if (i >= n) return;
    ushort4 hv = *(const ushort4*)(f + (size_t)i * 256 + lane * 4);
    float4 as = *(const float4*)(a_s + lane * 4);
    float4 ad = *(const float4*)(a_d + lane * 4);
    float x0 = bf16f(hv.x), x1 = bf16f(hv.y), x2 = bf16f(hv.z), x3 = bf16f(hv.w);
    float ps = x0 * as.x + x1 * as.y + x2 * as.z + x3 * as.w;
    float pd = x0 * ad.x + x1 * ad.y + x2 * ad.z + x3 * ad.w;
    #pragma unroll
    for (int ofs = 1; ofs < 16; ofs <<= 1) {
        ps += __shfl_xor(ps, ofs);
        pd += __shfl_xor(pd, ofs);
    }
    if ((lane & 15) == 0) {
        int hd = lane >> 4;
        al_s[(size_t)i * 4 + hd] = ps;
        al_d[(size_t)i * 4 + hd] = pd;
    }
}

// ---------------- softmax weights ----------------

__global__ void softmax4_kernel(const float* __restrict__ al_s, const float* __restrict__ al_d,
                                const int* __restrict__ row_ptr, const int* __restrict__ csr_src,
                                float* __restrict__ w4, int n) {
    int i = blockIdx.x * 4 + (threadIdx.x >> 6);
    int lane = threadIdx.x & 63;
    if (i >= n) return;
    int beg = row_ptr[i], end = row_ptr[i + 1];
    int h = lane & 3;
    int eo = lane >> 2;
    float ald = al_d[(size_t)i * 4 + h];
    float m = -1e30f;
    for (int base = beg; base < end; base += 16) {
        int e = base + eo;
        if (e < end) {
            float v = al_s[(size_t)csr_src[e] * 4 + h] + ald;
            v = v > 0.f ? v : 0.2f * v;
            m = fmaxf(m, v);
        }
    }
    #pragma unroll
    for (int ofs = 4; ofs <= 32; ofs <<= 1) m = fmaxf(m, __shfl_xor(m, ofs));
    float S = 0.f;
    for (int base = beg; base < end; base += 16) {
        int e = base + eo;
        if (e < end) {
            float v = al_s[(size_t)csr_src[e] * 4 + h] + ald;
            v = v > 0.f ? v : 0.2f * v;
            S += __expf(v - m);
        }
    }
    #pragma unroll
    for (int ofs = 4; ofs <= 32; ofs <<= 1) S += __shfl_xor(S, ofs);
    float inv = 1.f / (S + 1e-16f);
    for (int base = beg; base < end; base += 16) {
        int e = base + eo;
        if (e < end) {
            float v = al_s[(size_t)csr_src[e] * 4 + h] + ald;
            v = v > 0.f ? v : 0.2f * v;
            w4[(size_t)e * 4 + h] = __expf(v - m) * inv;
        }
    }
}

// layer 3: al[i*12 + h] = src logits, al[i*12 + 6 + h] = dst logits
__global__ void softmax6_kernel(const float* __restrict__ al, const int* __restrict__ row_ptr,
                                const int* __restrict__ csr_src, float* __restrict__ w6, int n) {
    int i = blockIdx.x * 4 + (threadIdx.x >> 6);
    int lane = threadIdx.x & 63;
    if (i >= n) return;
    int beg = row_ptr[i], end = row_ptr[i + 1];
    int h = lane & 7;
    int eo = lane >> 3;
    bool act = h < 6;
    float ald = act ? al[(size_t)i * 12 + 6 + h] : 0.f;
    float m = -1e30f;
    for (int base = beg; base < end; base += 8) {
        int e = base + eo;
        if (act && e < end) {
            float v = al[(size_t)csr_src[e] * 12 + h] + ald;
            v = v > 0.f ? v : 0.2f * v;
            m = fmaxf(m, v);
        }
    }
    #pragma unroll
    for (int ofs = 8; ofs <= 32; ofs <<= 1) m = fmaxf(m, __shfl_xor(m, ofs));
    float S = 0.f;
    for (int base = beg; base < end; base += 8) {
        int e = base + eo;
        if (act && e < end) {
            float v = al[(size_t)csr_src[e] * 12 + h] + ald;
            v = v > 0.f ? v : 0.2f * v;
            S += __expf(v - m);
        }
    }
    #pragma unroll
    for (int ofs = 8; ofs <= 32; ofs <<= 1) S += __shfl_xor(S, ofs);
    float inv = 1.f / (S + 1e-16f);
    for (int base = beg; base < end; base += 8) {
        int e = base + eo;
        if (act && e < end) {
            float v = al[(size_t)csr_src[e] * 12 + h] + ald;
            v = v > 0.f ? v : 0.2f * v;
            w6[(size_t)e * 6 + h] = __expf(v - m) * inv;
        }
    }
}

// ---------------- aggregation, layers 1&2: block(256) per node, bf16 gather ----------------

__global__ __launch_bounds__(256) void agg_concat_b16(
    const u16* __restrict__ f, const float* __restrict__ w4,
    const int* __restrict__ row_ptr, const int* __restrict__ csr_src,
    const float* __restrict__ bias, const float* __restrict__ res,
    u16* __restrict__ outb, int node0) {
    __shared__ int s_idx[64];
    __shared__ float s_w[64][4];
    int i = node0 + blockIdx.x;
    int tid = threadIdx.x;
    int hd = tid >> 6;
    int beg = row_ptr[i], end = row_ptr[i + 1];
    float acc = 0.f;
    for (int base = beg; base < end; base += 64) {
        int cnt = min(64, end - base);
        __syncthreads();
        if (tid < cnt) {
            int e = base + tid;
            s_idx[tid] = csr_src[e];
            float4 ww = ((const float4*)w4)[e];
            s_w[tid][0] = ww.x; s_w[tid][1] = ww.y; s_w[tid][2] = ww.z; s_w[tid][3] = ww.w;
        }
        __syncthreads();
        int c = 0;
        for (; c + 4 <= cnt; c += 4) {
            int s0 = s_idx[c], s1 = s_idx[c + 1], s2 = s_idx[c + 2], s3 = s_idx[c + 3];
            float w0 = s_w[c][hd], w1 = s_w[c + 1][hd], w2 = s_w[c + 2][hd], w3 = s_w[c + 3][hd];
            float v0 = bf16f(f[(size_t)s0 * 256 + tid]);
            float v1 = bf16f(f[(size_t)s1 * 256 + tid]);
            float v2 = bf16f(f[(size_t)s2 * 256 + tid]);
            float v3 = bf16f(f[(size_t)s3 * 256 + tid]);
            acc += w0 * v0; acc += w1 * v1; acc += w2 * v2; acc += w3 * v3;
        }
        for (; c < cnt; c++) acc += s_w[c][hd] * bf16f(f[(size_t)s_idx[c] * 256 + tid]);
    }
    float v = acc + bias[tid];
    if (res) v += res[(size_t)blockIdx.x * 256 + tid];
    v = v > 0.f ? v : (__expf(v) - 1.f);  // ELU
    outb[(size_t)i * 256 + tid] = f2b(v);
}

// ---------------- layer 3: S[i, h*256+tid] = (1/6) sum_j w6[j,h] * x[src_j, tid] ----------------

__global__ __launch_bounds__(256) void aggS_kernel(
    const u16* __restrict__ x, const float* __restrict__ w6,
    const int* __restrict__ row_ptr, const int* __restrict__ csr_src,
    u16* __restrict__ S, int node0) {
    __shared__ int s_idx[32];
    __shared__ float s_w[192];
    int i = node0 + blockIdx.x;
    int tid = threadIdx.x;
    int beg = row_ptr[i], end = row_ptr[i + 1];
    float acc[6] = {0.f, 0.f, 0.f, 0.f, 0.f, 0.f};
    for (int base = beg; base < end; base += 32) {
        int cnt = min(32, end - base);
        __syncthreads();
        if (tid < cnt) s_idx[tid] = csr_src[base + tid];
        if (tid < cnt * 6) s_w[tid] = w6[(size_t)base * 6 + tid];
        __syncthreads();
        int c = 0;
        for (; c + 2 <= cnt; c += 2) {
            float v0 = bf16f(x[(size_t)s_idx[c] * 256 + tid]);
            float v1 = bf16f(x[(size_t)s_idx[c + 1] * 256 + tid]);
            #pragma unroll
            for (int h = 0; h < 6; h++) {
                acc[h] += s_w[c * 6 + h] * v0;
                acc[h] += s_w[c * 6 + 6 + h] * v1;
            }
        }
        for (; c < cnt; c++) {
            float v = bf16f(x[(size_t)s_idx[c] * 256 + tid]);
            #pragma unroll
            for (int h = 0; h < 6; h++) acc[h] += s_w[c * 6 + h] * v;
        }
    }
    #pragma unroll
    for (int h = 0; h < 6; h++)
        S[(size_t)blockIdx.x * 1536 + h * 256 + tid] = f2b(acc[h] * (1.f / 6.f));
}

// ---------------- host ----------------

extern "C" void kernel_launch(void* const* d_in, const int* in_sizes, int n_in,
                              void* d_out, int out_size, void* d_ws, size_t ws_size,
                              hipStream_t stream) {
    const float* x      = (const float*)d_in[0];
    const int*   src    = (const int*)d_in[1];
    const int*   dst    = (const int*)d_in[2];
    const float* W1     = (const float*)d_in[3];
    const float* a1_src = (const float*)d_in[4];
    const float* a1_dst = (const float*)d_in[5];
    const float* b1     = (const float*)d_in[6];
    const float* W2     = (const float*)d_in[7];
    const float* a2_src = (const float*)d_in[8];
    const float* a2_dst = (const float*)d_in[9];
    const float* b2     = (const float*)d_in[10];
    const float* Wres2  = (const float*)d_in[11];
    const float* W3     = (const float*)d_in[12];
    const float* a3_src = (const float*)d_in[13];
    const float* a3_dst = (const float*)d_in[14];
    const float* b3     = (const float*)d_in[15];
    float* out = (float*)d_out;

    const int N = NODES, E = EDGES;
    const int EN = E + N;

    char* p = (char*)d_ws;
    auto alloc = [&](size_t bytes) -> char* {
        char* r = p;
        p += (bytes + 511) & ~(size_t)511;
        return r;
    };
    // persistent
    int*   row_ptr = (int*)alloc((size_t)(N + 1) * sizeof(int));
    int*   cursor  = (int*)alloc((size_t)N * sizeof(int));
    int*   deg     = (int*)alloc((size_t)N * sizeof(int));
    int*   csr_src = (int*)alloc((size_t)EN * sizeof(int));
    float* al      = (float*)alloc((size_t)N * 12 * sizeof(float));  // L1/2: al_s=al, al_d=al+4N
    float* wbuf    = (float*)alloc((size_t)EN * 6 * sizeof(float));  // w4 (4-plane) / w6 (6-plane)
    u16*   o2b     = (u16*)alloc((size_t)MPAD * 256 * sizeof(u16));  // layer-2 output bf16
    u16*   WT2     = (u16*)alloc((size_t)256 * 256 * sizeof(u16));
    u16*   cmT     = (u16*)alloc((size_t)128 * 256 * sizeof(u16));
    u16*   W3sT    = (u16*)alloc((size_t)128 * 1536 * sizeof(u16));
    // region2 (phase-overlaid)
    const size_t A2B_B = (size_t)MPAD * 256 * sizeof(u16);   // 25,624,576
    const size_t F1B_B = (size_t)N * 256 * sizeof(u16);      // 25,600,000
    const size_t O1C_B = (size_t)C0 * 256 * sizeof(float);   // 25,690,112
    const size_t S_B   = (size_t)C0 * 1536 * sizeof(u16);    // 77,070,336
    size_t r2_bytes = A2B_B + F1B_B + O1C_B;
    if (S_B > r2_bytes) r2_bytes = S_B;
    char* r2 = alloc(r2_bytes + 1024);
    u16*   A2b = (u16*)r2;                       // layer-1 output bf16 [MPAD,256]
    u16*   f1b = (u16*)(r2 + A2B_B);             // h (gather src) bf16 [N,256]
    float* o1c = (float*)(r2 + A2B_B + F1B_B);   // residual chunk fp32 [C0,256]
    u16*   A2a = (u16*)(r2 + A2B_B + F1B_B);     // x bf16 [MPAD,128] (dead before o1c)
    u16*   Sb  = (u16*)r2;                       // S chunk bf16 [C0,1536] (phase B)
    (void)ws_size; (void)n_in; (void)in_sizes; (void)out_size;

    float* al_s = al;
    float* al_d = al + (size_t)4 * N;

    // --- CSR build ---
    fill_ones_kernel<<<(N + 255) / 256, 256, 0, stream>>>(deg, N);
    hist_kernel<<<(E + 255) / 256, 256, 0, stream>>>(dst, deg, E);
    scan_kernel<<<1, 1024, 0, stream>>>(deg, row_ptr, cursor, N);
    scatter_kernel<<<(E + N + 255) / 256, 256, 0, stream>>>(src, dst, E, N, cursor, csr_src);

    int nwb = (N + 3) / 4;

    // --- layer 1: 128 -> 4x64 concat, ELU ---
    convertA4_kernel<<<(N * 128 / 4 + 255) / 256, 256, 0, stream>>>(x, A2a, N * 128 / 4);
    convertW_kernel<<<(256 * 128 + 255) / 256, 256, 0, stream>>>(W1, 256, 0, 256, 256, 128, WT2);
    {
        dim3 g(MPAD / 128, 2);
        gemm_mfma_kernel<<<g, 256, 0, stream>>>(A2a, WT2, nullptr, f1b, N, 256, 128, 256, nullptr, 0);
    }
    row_alpha4_kernel<<<nwb, 256, 0, stream>>>(f1b, a1_src, a1_dst, al_s, al_d, N);
    softmax4_kernel<<<nwb, 256, 0, stream>>>(al_s, al_d, row_ptr, csr_src, wbuf, N);
    agg_concat_b16<<<N, 256, 0, stream>>>(f1b, wbuf, row_ptr, csr_src, b1, nullptr, A2b, 0);

    // --- layer 2: 256 -> 4x64 concat + residual, ELU ---
    convertW_kernel<<<(256 * 256 + 255) / 256, 256, 0, stream>>>(W2, 256, 0, 256, 256, 256, WT2);
    {
        dim3 g(MPAD / 128, 2);
        gemm_mfma_kernel<<<g, 256, 0, stream>>>(A2b, WT2, nullptr, f1b, N, 256, 256, 256, nullptr, 0);
    }
    row_alpha4_kernel<<<nwb, 256, 0, stream>>>(f1b, a2_src, a2_dst, al_s, al_d, N);
    softmax4_kernel<<<nwb, 256, 0, stream>>>(al_s, al_d, row_ptr, csr_src, wbuf, N);
    convertW_kernel<<<(256 * 256 + 255) / 256, 256, 0, stream>>>(Wres2, 256, 0, 256, 256, 256, WT2);
    {
        // chunk 0
        dim3 g0(C0 / 128, 2);
        gemm_mfma_kernel<<<g0, 256, 0, stream>>>(A2b, WT2, o1c, nullptr, C0, 256, 256, 256, nullptr, 0);
        agg_concat_b16<<<C0, 256, 0, stream>>>(f1b, wbuf, row_ptr, csr_src, b2, o1c, o2b, 0);
        // chunk 1
        dim3 g1(C1R / 128, 2);
        gemm_mfma_kernel<<<g1, 256, 0, stream>>>(A2b + (size_t)C0 * 256, WT2, o1c, nullptr,
                                                 N - C0, 256, 256, 256, nullptr, 0);
        agg_concat_b16<<<N - C0, 256, 0, stream>>>(f1b, wbuf, row_ptr, csr_src, b2, o1c, o2b, C0);
    }

    // --- layer 3: input-space aggregation + one fused GEMM ---
    prep_cmat_kernel<<<(128 * 256 + 255) / 256, 256, 0, stream>>>(W3, a3_src, a3_dst, cmT);
    {
        dim3 g(MPAD / 128, 1);
        gemm_mfma_kernel<<<g, 256, 0, stream>>>(o2b, cmT, al, nullptr, N, 12, 256, 12, nullptr, 0);
    }
    softmax6_kernel<<<nwb, 256, 0, stream>>>(al, row_ptr, csr_src, wbuf, N);
    convertW3stack_kernel<<<(128 * 1536 + 255) / 256, 256, 0, stream>>>(W3, W3sT);
    {
        // chunk 0
        aggS_kernel<<<C0, 256, 0, stream>>>(o2b, wbuf, row_ptr, csr_src, Sb, 0);
        dim3 g0(C0 / 128, 1);
        gemm_mfma_kernel<<<g0, 256, 0, stream>>>(Sb, W3sT, out, nullptr, C0, 121, 1536, 121, b3, 1);
        // chunk 1
        aggS_kernel<<<N - C0, 256, 0, stream>>>(o2b, wbuf, row_ptr, csr_src, Sb, C0);
        dim3 g1(C1R / 128, 1);
        gemm_mfma_kernel<<<g1, 256, 0, stream>>>(Sb, W3sT, out + (size_t)C0 * 121, nullptr,
                                                 N - C0, 121, 1536, 121, b3, 1);
    }
}

// Round 4
// 734.403 us; speedup vs baseline: 3.4573x; 1.2173x over previous
//
#include <hip/hip_runtime.h>
#include <hip/hip_bf16.h>

// PPI GAT, 3 layers. N=50000, E=800000 (+N self loops), avg degree ~17.
// R4: wave-per-node gathers (uint2 vector loads, shfl-broadcast edge staging),
//     2-pass softmax with deferred 1/S normalization, parallel CSR scan.

#define NODES 50000
#define EDGES 800000
#define MPAD  50048            // ceil(N/128)*128
#define C0    25088            // chunk-0 rows (196 tiles)
#define C1R   24960            // chunk-1 padded rows (195 tiles)

typedef unsigned short u16;
typedef __attribute__((ext_vector_type(8))) short bf16x8;
typedef __attribute__((ext_vector_type(4))) float f32x4;

__device__ __forceinline__ float bf16f(u16 r) {
    return __uint_as_float(((unsigned)r) << 16);
}
__device__ __forceinline__ u16 f2b(float v) {
    __hip_bfloat16 b = __float2bfloat16(v);
    return *(u16*)&b;
}
__device__ __forceinline__ float blo(unsigned d) { return __uint_as_float(d << 16); }
__device__ __forceinline__ float bhi(unsigned d) { return __uint_as_float(d & 0xffff0000u); }

// ---------------- CSR build ----------------

__global__ void fill_ones_kernel(int* __restrict__ deg, int n) {
    int i = blockIdx.x * blockDim.x + threadIdx.x;
    if (i < n) deg[i] = 1;  // self-loop
}

__global__ void hist_kernel(const int* __restrict__ dst, int* __restrict__ deg, int E) {
    int e = blockIdx.x * blockDim.x + threadIdx.x;
    if (e < E) atomicAdd(&deg[dst[e]], 1);
}

// 3-kernel parallel scan: block sums -> scan sums -> block rescan
__global__ void deg_bsum_kernel(const int* __restrict__ deg, int* __restrict__ bsum, int n) {
    int tid = threadIdx.x, lane = tid & 63, wid = tid >> 6;
    int i = blockIdx.x * 256 + tid;
    int v = (i < n) ? deg[i] : 0;
    #pragma unroll
    for (int ofs = 32; ofs > 0; ofs >>= 1) v += __shfl_down(v, ofs);
    __shared__ int sp[4];
    if (lane == 0) sp[wid] = v;
    __syncthreads();
    if (tid == 0) bsum[blockIdx.x] = sp[0] + sp[1] + sp[2] + sp[3];
}

__global__ void bsum_scan_kernel(int* __restrict__ bsum, int* __restrict__ row_ptr,
                                 int nb, int n) {
    int tid = threadIdx.x, lane = tid & 63, wid = tid >> 6;
    int v = (tid < nb) ? bsum[tid] : 0;
    int incl = v;
    #pragma unroll
    for (int ofs = 1; ofs < 64; ofs <<= 1) {
        int t = __shfl_up(incl, ofs);
        if (lane >= ofs) incl += t;
    }
    __shared__ int sp[4];
    if (lane == 63) sp[wid] = incl;
    __syncthreads();
    int add = 0;
    for (int k = 0; k < wid; k++) add += sp[k];
    int excl = incl - v + add;
    if (tid < nb) bsum[tid] = excl;
    if (tid == nb - 1) row_ptr[n] = excl + v;
}

__global__ void deg_scan_kernel(const int* __restrict__ deg, const int* __restrict__ bofs,
                                int* __restrict__ row_ptr, int* __restrict__ cursor, int n) {
    int tid = threadIdx.x, lane = tid & 63, wid = tid >> 6;
    int i = blockIdx.x * 256 + tid;
    int v = (i < n) ? deg[i] : 0;
    int incl = v;
    #pragma unroll
    for (int ofs = 1; ofs < 64; ofs <<= 1) {
        int t = __shfl_up(incl, ofs);
        if (lane >= ofs) incl += t;
    }
    __shared__ int sp[4];
    if (lane == 63) sp[wid] = incl;
    __syncthreads();
    int add = bofs[blockIdx.x];
    for (int k = 0; k < wid; k++) add += sp[k];
    int excl = incl - v + add;
    if (i < n) { row_ptr[i] = excl; cursor[i] = excl; }
}

__global__ void scatter_kernel(const int* __restrict__ src, const int* __restrict__ dst,
                               int E, int n, int* __restrict__ cursor, int* __restrict__ csr_src) {
    int e = blockIdx.x * blockDim.x + threadIdx.x;
    if (e < E) {
        int d = dst[e];
        int p = atomicAdd(&cursor[d], 1);
        csr_src[p] = src[e];
    } else if (e < E + n) {
        int i = e - E;
        int p = atomicAdd(&cursor[i], 1);
        csr_src[p] = i;  // self-loop
    }
}

// ---------------- converts ----------------

__global__ void convertA4_kernel(const float* __restrict__ A, u16* __restrict__ O, int total4) {
    int idx = blockIdx.x * blockDim.x + threadIdx.x;
    if (idx >= total4) return;
    float4 f = ((const float4*)A)[idx];
    ushort4 o;
    o.x = f2b(f.x); o.y = f2b(f.y); o.z = f2b(f.z); o.w = f2b(f.w);
    ((ushort4*)O)[idx] = o;
}

__global__ void convertW_kernel(const float* __restrict__ W, int ldw, int col0,
                                int Ncols, int Npad, int K, u16* __restrict__ WT) {
    int idx = blockIdx.x * blockDim.x + threadIdx.x;
    if (idx >= Npad * K) return;
    int k = idx % K;
    int n = idx / K;
    float f = (n < Ncols) ? W[(size_t)k * ldw + col0 + n] : 0.f;
    WT[(size_t)n * K + k] = f2b(f);
}

__global__ void convertW3stack_kernel(const float* __restrict__ W3, u16* __restrict__ WT) {
    int idx = blockIdx.x * blockDim.x + threadIdx.x;
    if (idx >= 128 * 1536) return;
    int q = idx % 1536;
    int n = idx / 1536;
    int h = q >> 8, k = q & 255;
    float f = (n < 121) ? W3[(size_t)k * 726 + h * 121 + n] : 0.f;
    WT[(size_t)n * 1536 + q] = f2b(f);
}

__global__ void prep_cmat_kernel(const float* __restrict__ W3, const float* __restrict__ a3s,
                                 const float* __restrict__ a3d, u16* __restrict__ cmT) {
    int idx = blockIdx.x * blockDim.x + threadIdx.x;
    if (idx >= 128 * 256) return;
    int k = idx & 255;
    int o = idx >> 8;
    float v = 0.f;
    if (o < 12) {
        int h = o % 6;
        const float* a = (o < 6) ? a3s : a3d;
        for (int c = 0; c < 121; c++) v += W3[(size_t)k * 726 + h * 121 + c] * a[h * 121 + c];
    }
    cmT[(size_t)o * 256 + k] = f2b(v);
}

// ---------------- bf16 MFMA GEMM ----------------

__global__ __launch_bounds__(256) void gemm_mfma_kernel(
    const u16* __restrict__ A, const u16* __restrict__ B,
    float* __restrict__ Cf, u16* __restrict__ Cb,
    int M, int Ncols, int K2, int ldc,
    const float* __restrict__ bias, int act) {
    __shared__ __align__(16) u16 As[128][40];
    __shared__ __align__(16) u16 Bs[128][40];
    int tid = threadIdx.x;
    int lane = tid & 63;
    int wv = tid >> 6;
    int quad = lane >> 4, lm = lane & 15;
    int wm = (wv & 1) * 64, wn = (wv >> 1) * 64;
    int bm = blockIdx.x * 128, bn = blockIdx.y * 128;

    f32x4 zero = {0.f, 0.f, 0.f, 0.f};
    f32x4 acc[4][4];
    #pragma unroll
    for (int i = 0; i < 4; i++)
        #pragma unroll
        for (int j = 0; j < 4; j++) acc[i][j] = zero;

    for (int k0 = 0; k0 < K2; k0 += 32) {
        #pragma unroll
        for (int it = 0; it < 2; ++it) {
            int chunk = tid + it * 256;
            int row = chunk >> 2, seg = chunk & 3;
            uint4 va = *(const uint4*)(A + (size_t)(bm + row) * K2 + k0 + seg * 8);
            uint4 vb = *(const uint4*)(B + (size_t)(bn + row) * K2 + k0 + seg * 8);
            *(uint4*)&As[row][seg * 8] = va;
            *(uint4*)&Bs[row][seg * 8] = vb;
        }
        __syncthreads();
        bf16x8 af[4], bfr[4];
        #pragma unroll
        for (int i = 0; i < 4; i++) af[i] = *(const bf16x8*)&As[wm + i * 16 + lm][quad * 8];
        #pragma unroll
        for (int j = 0; j < 4; j++) bfr[j] = *(const bf16x8*)&Bs[wn + j * 16 + lm][quad * 8];
        #pragma unroll
        for (int i = 0; i < 4; i++)
            #pragma unroll
            for (int j = 0; j < 4; j++)
                acc[i][j] = __builtin_amdgcn_mfma_f32_16x16x32_bf16(af[i], bfr[j], acc[i][j], 0, 0, 0);
        __syncthreads();
    }

    #pragma unroll
    for (int i = 0; i < 4; i++) {
        #pragma unroll
        for (int j = 0; j < 4; j++) {
            int col = bn + wn + j * 16 + lm;
            if (col >= Ncols) continue;
            int row_base = bm + wm + i * 16 + quad * 4;
            #pragma unroll
            for (int r = 0; r < 4; r++) {
                int row = row_base + r;
                if (row >= M) continue;
                float v = acc[i][j][r];
                if (act == 1) {
                    v += bias[col];
                    v = 1.f / (1.f + __expf(-v));
                }
                if (Cf) Cf[(size_t)row * ldc + col] = v;
                else    Cb[(size_t)row * ldc + col] = f2b(v);
            }
        }
    }
}

// ---------------- attention logits, layers 1&2 ----------------

__global__ void row_alpha4_kernel(const u16* __restrict__ f, const float* __restrict__ a_s,
                                  const float* __restrict__ a_d, float* __restrict__ al_s,
                                  float* __restrict__ al_d, int n) {
    int wv = threadIdx.x >> 6, lane = threadIdx.x & 63;
    int i = blockIdx.x * 4 + wv;
    if (i >= n) return;
    ushort4 hv = *(const ushort4*)(f + (size_t)i * 256 + lane * 4);
    float4 as = *(const float4*)(a_s + lane * 4);
    float4 ad = *(const float4*)(a_d + lane * 4);
    float x0 = bf16f(hv.x), x1 = bf16f(hv.y), x2 = bf16f(hv.z), x3 = bf16f(hv.w);
    float ps = x0 * as.x + x1 * as.y + x2 * as.z + x3 * as.w;
    float pd = x0 * ad.x + x1 * ad.y + x2 * ad.z + x3 * ad.w;
    #pragma unroll
    for (int ofs = 1; ofs < 16; ofs <<= 1) {
        ps += __shfl_xor(ps, ofs);
        pd += __shfl_xor(pd, ofs);
    }
    if ((lane & 15) == 0) {
        int hd = lane >> 4;
        al_s[(size_t)i * 4 + hd] = ps;
        al_d[(size_t)i * 4 + hd] = pd;
    }
}

// ---------------- softmax: 2 passes, write unnormalized ex + inv ----------------

__global__ void softmax4_kernel(const float* __restrict__ al_s, const float* __restrict__ al_d,
                                const int* __restrict__ row_ptr, const int* __restrict__ csr_src,
                                float* __restrict__ w4, float* __restrict__ inv4, int n) {
    int i = blockIdx.x * 4 + (threadIdx.x >> 6);
    int lane = threadIdx.x & 63;
    if (i >= n) return;
    int beg = row_ptr[i], end = row_ptr[i + 1];
    int h = lane & 3;
    int eo = lane >> 2;
    float ald = al_d[(size_t)i * 4 + h];
    float m = -1e30f;
    for (int base = beg; base < end; base += 16) {
        int e = base + eo;
        if (e < end) {
            float v = al_s[(size_t)csr_src[e] * 4 + h] + ald;
            v = v > 0.f ? v : 0.2f * v;
            m = fmaxf(m, v);
        }
    }
    #pragma unroll
    for (int ofs = 4; ofs <= 32; ofs <<= 1) m = fmaxf(m, __shfl_xor(m, ofs));
    float S = 0.f;
    for (int base = beg; base < end; base += 16) {
        int e = base + eo;
        if (e < end) {
            float v = al_s[(size_t)csr_src[e] * 4 + h] + ald;
            v = v > 0.f ? v : 0.2f * v;
            float ex = __expf(v - m);
            w4[(size_t)e * 4 + h] = ex;
            S += ex;
        }
    }
    #pragma unroll
    for (int ofs = 4; ofs <= 32; ofs <<= 1) S += __shfl_xor(S, ofs);
    if (eo == 0) inv4[(size_t)i * 4 + h] = 1.f / (S + 1e-16f);
}

// layer 3: al[i*12 + h] = src logits, al[i*12 + 6 + h] = dst logits; inv6 folds 1/6
__global__ void softmax6_kernel(const float* __restrict__ al, const int* __restrict__ row_ptr,
                                const int* __restrict__ csr_src, float* __restrict__ w6,
                                float* __restrict__ inv6, int n) {
    int i = blockIdx.x * 4 + (threadIdx.x >> 6);
    int lane = threadIdx.x & 63;
    if (i >= n) return;
    int beg = row_ptr[i], end = row_ptr[i + 1];
    int h = lane & 7;
    int eo = lane >> 3;
    bool act = h < 6;
    float ald = act ? al[(size_t)i * 12 + 6 + h] : 0.f;
    float m = -1e30f;
    for (int base = beg; base < end; base += 8) {
        int e = base + eo;
        if (act && e < end) {
            float v = al[(size_t)csr_src[e] * 12 + h] + ald;
            v = v > 0.f ? v : 0.2f * v;
            m = fmaxf(m, v);
        }
    }
    #pragma unroll
    for (int ofs = 8; ofs <= 32; ofs <<= 1) m = fmaxf(m, __shfl_xor(m, ofs));
    float S = 0.f;
    for (int base = beg; base < end; base += 8) {
        int e = base + eo;
        if (act && e < end) {
            float v = al[(size_t)csr_src[e] * 12 + h] + ald;
            v = v > 0.f ? v : 0.2f * v;
            float ex = __expf(v - m);
            w6[(size_t)e * 6 + h] = ex;
            S += ex;
        }
    }
    #pragma unroll
    for (int ofs = 8; ofs <= 32; ofs <<= 1) S += __shfl_xor(S, ofs);
    if (eo == 0 && act) inv6[(size_t)i * 6 + h] = 1.f / (6.f * (S + 1e-16f));
}

// ---------------- agg layers 1&2: WAVE per node, lane = 4 channels ----------------
// 16-edge register staging broadcast via shfl; epilogue applies inv, bias, res, ELU.

__global__ __launch_bounds__(256) void agg4_wave(
    const u16* __restrict__ f, const float* __restrict__ w4, const float* __restrict__ inv4,
    const int* __restrict__ row_ptr, const int* __restrict__ csr_src,
    const float* __restrict__ bias, const float* __restrict__ res,
    u16* __restrict__ outb, int node0, int count) {
    int wid = threadIdx.x >> 6, lane = threadIdx.x & 63;
    int li = blockIdx.x * 4 + wid;
    if (li >= count) return;
    int i = node0 + li;
    int beg = row_ptr[i], end = row_ptr[i + 1];
    int h = lane >> 4;
    int c4 = lane * 4;
    int el = lane & 15;
    float acc0 = 0.f, acc1 = 0.f, acc2 = 0.f, acc3 = 0.f;
    for (int base = beg; base < end; base += 16) {
        int cnt = min(16, end - base);
        int ee = base + min(el, cnt - 1);
        int idxv = csr_src[ee];
        float wv = w4[(size_t)ee * 4 + h];
        int e = 0;
        for (; e + 2 <= cnt; e += 2) {
            int s0 = __shfl(idxv, e);
            int s1 = __shfl(idxv, e + 1);
            float w0 = __shfl(wv, (lane & 48) | e);
            float w1 = __shfl(wv, (lane & 48) | (e + 1));
            uint2 d0 = *(const uint2*)(f + (size_t)s0 * 256 + c4);
            uint2 d1 = *(const uint2*)(f + (size_t)s1 * 256 + c4);
            acc0 = fmaf(w0, blo(d0.x), acc0); acc1 = fmaf(w0, bhi(d0.x), acc1);
            acc2 = fmaf(w0, blo(d0.y), acc2); acc3 = fmaf(w0, bhi(d0.y), acc3);
            acc0 = fmaf(w1, blo(d1.x), acc0); acc1 = fmaf(w1, bhi(d1.x), acc1);
            acc2 = fmaf(w1, blo(d1.y), acc2); acc3 = fmaf(w1, bhi(d1.y), acc3);
        }
        if (e < cnt) {
            int s0 = __shfl(idxv, e);
            float w0 = __shfl(wv, (lane & 48) | e);
            uint2 d0 = *(const uint2*)(f + (size_t)s0 * 256 + c4);
            acc0 = fmaf(w0, blo(d0.x), acc0); acc1 = fmaf(w0, bhi(d0.x), acc1);
            acc2 = fmaf(w0, blo(d0.y), acc2); acc3 = fmaf(w0, bhi(d0.y), acc3);
        }
    }
    float inv = inv4[(size_t)i * 4 + h];
    float4 b = *(const float4*)(bias + c4);
    float v0 = acc0 * inv + b.x;
    float v1 = acc1 * inv + b.y;
    float v2 = acc2 * inv + b.z;
    float v3 = acc3 * inv + b.w;
    if (res) {
        float4 r = *(const float4*)(res + (size_t)li * 256 + c4);
        v0 += r.x; v1 += r.y; v2 += r.z; v3 += r.w;
    }
    v0 = v0 > 0.f ? v0 : (__expf(v0) - 1.f);
    v1 = v1 > 0.f ? v1 : (__expf(v1) - 1.f);
    v2 = v2 > 0.f ? v2 : (__expf(v2) - 1.f);
    v3 = v3 > 0.f ? v3 : (__expf(v3) - 1.f);
    ushort4 o;
    o.x = f2b(v0); o.y = f2b(v1); o.z = f2b(v2); o.w = f2b(v3);
    *(ushort4*)(outb + (size_t)i * 256 + c4) = o;
}

// ---------------- layer 3 S-aggregation: WAVE per node, 6 heads ----------------
// S[li, h*256 + c] = inv6[i,h] * sum_j w6[j,h] * x[src_j, c]

__global__ __launch_bounds__(256) void aggS_wave(
    const u16* __restrict__ x, const float* __restrict__ w6, const float* __restrict__ inv6,
    const int* __restrict__ row_ptr, const int* __restrict__ csr_src,
    u16* __restrict__ S, int node0, int count) {
    __shared__ int s_i[4][16];
    __shared__ float s_w[4][96];
    int wid = threadIdx.x >> 6, lane = threadIdx.x & 63;
    int li = blockIdx.x * 4 + wid;
    if (li >= count) return;
    int i = node0 + li;
    int beg = row_ptr[i], end = row_ptr[i + 1];
    int c4 = lane * 4;
    float acc[6][4] = {};
    for (int base = beg; base < end; base += 16) {
        int cnt = min(16, end - base);
        if (lane < cnt) s_i[wid][lane] = csr_src[base + lane];
        int nw = cnt * 6;
        if (lane < nw) s_w[wid][lane] = w6[(size_t)base * 6 + lane];
        if (lane + 64 < nw) s_w[wid][lane + 64] = w6[(size_t)base * 6 + lane + 64];
        // wave-coherent LDS: lockstep write->read, no barrier needed
        for (int e = 0; e < cnt; e++) {
            int s = s_i[wid][e];
            uint2 d = *(const uint2*)(x + (size_t)s * 256 + c4);
            float v0 = blo(d.x), v1 = bhi(d.x), v2 = blo(d.y), v3 = bhi(d.y);
            #pragma unroll
            for (int hh = 0; hh < 6; hh++) {
                float w = s_w[wid][e * 6 + hh];
                acc[hh][0] = fmaf(w, v0, acc[hh][0]);
                acc[hh][1] = fmaf(w, v1, acc[hh][1]);
                acc[hh][2] = fmaf(w, v2, acc[hh][2]);
                acc[hh][3] = fmaf(w, v3, acc[hh][3]);
            }
        }
    }
    #pragma unroll
    for (int hh = 0; hh < 6; hh++) {
        float inv = inv6[(size_t)i * 6 + hh];
        ushort4 o;
        o.x = f2b(acc[hh][0] * inv);
        o.y = f2b(acc[hh][1] * inv);
        o.z = f2b(acc[hh][2] * inv);
        o.w = f2b(acc[hh][3] * inv);
        *(ushort4*)(S + (size_t)li * 1536 + hh * 256 + c4) = o;
    }
}

// ---------------- host ----------------

extern "C" void kernel_launch(void* const* d_in, const int* in_sizes, int n_in,
                              void* d_out, int out_size, void* d_ws, size_t ws_size,
                              hipStream_t stream) {
    const float* x      = (const float*)d_in[0];
    const int*   src    = (const int*)d_in[1];
    const int*   dst    = (const int*)d_in[2];
    const float* W1     = (const float*)d_in[3];
    const float* a1_src = (const float*)d_in[4];
    const float* a1_dst = (const float*)d_in[5];
    const float* b1     = (const float*)d_in[6];
    const float* W2     = (const float*)d_in[7];
    const float* a2_src = (const float*)d_in[8];
    const float* a2_dst = (const float*)d_in[9];
    const float* b2     = (const float*)d_in[10];
    const float* Wres2  = (const float*)d_in[11];
    const float* W3     = (const float*)d_in[12];
    const float* a3_src = (const float*)d_in[13];
    const float* a3_dst = (const float*)d_in[14];
    const float* b3     = (const float*)d_in[15];
    float* out = (float*)d_out;

    const int N = NODES, E = EDGES;
    const int EN = E + N;
    const int NB = (N + 255) / 256;  // 196

    char* p = (char*)d_ws;
    auto alloc = [&](size_t bytes) -> char* {
        char* r = p;
        p += (bytes + 511) & ~(size_t)511;
        return r;
    };
    // persistent
    int*   row_ptr = (int*)alloc((size_t)(N + 1) * sizeof(int));
    int*   cursor  = (int*)alloc((size_t)N * sizeof(int));
    int*   deg     = (int*)alloc((size_t)N * sizeof(int));
    int*   bsum    = (int*)alloc(256 * sizeof(int));
    int*   csr_src = (int*)alloc((size_t)EN * sizeof(int));
    float* al      = (float*)alloc((size_t)N * 12 * sizeof(float));
    float* inv4    = (float*)alloc((size_t)N * 4 * sizeof(float));
    float* inv6    = (float*)alloc((size_t)N * 6 * sizeof(float));
    float* wbuf    = (float*)alloc((size_t)EN * 6 * sizeof(float));
    u16*   o2b     = (u16*)alloc((size_t)MPAD * 256 * sizeof(u16));
    u16*   WT2     = (u16*)alloc((size_t)256 * 256 * sizeof(u16));
    u16*   cmT     = (u16*)alloc((size_t)128 * 256 * sizeof(u16));
    u16*   W3sT    = (u16*)alloc((size_t)128 * 1536 * sizeof(u16));
    // region2 (phase-overlaid)
    const size_t A2B_B = (size_t)MPAD * 256 * sizeof(u16);
    const size_t F1B_B = (size_t)N * 256 * sizeof(u16);
    const size_t O1C_B = (size_t)C0 * 256 * sizeof(float);
    const size_t S_B   = (size_t)C0 * 1536 * sizeof(u16);
    size_t r2_bytes = A2B_B + F1B_B + O1C_B;
    if (S_B > r2_bytes) r2_bytes = S_B;
    char* r2 = alloc(r2_bytes + 1024);
    u16*   A2b = (u16*)r2;
    u16*   f1b = (u16*)(r2 + A2B_B);
    float* o1c = (float*)(r2 + A2B_B + F1B_B);
    u16*   A2a = (u16*)(r2 + A2B_B + F1B_B);
    u16*   Sb  = (u16*)r2;
    (void)ws_size; (void)n_in; (void)in_sizes; (void)out_size;

    float* al_s = al;
    float* al_d = al + (size_t)4 * N;

    // --- CSR build ---
    fill_ones_kernel<<<NB, 256, 0, stream>>>(deg, N);
    hist_kernel<<<(E + 255) / 256, 256, 0, stream>>>(dst, deg, E);
    deg_bsum_kernel<<<NB, 256, 0, stream>>>(deg, bsum, N);
    bsum_scan_kernel<<<1, 256, 0, stream>>>(bsum, row_ptr, NB, N);
    deg_scan_kernel<<<NB, 256, 0, stream>>>(deg, bsum, row_ptr, cursor, N);
    scatter_kernel<<<(E + N + 255) / 256, 256, 0, stream>>>(src, dst, E, N, cursor, csr_src);

    int nwb = (N + 3) / 4;

    // --- layer 1: 128 -> 4x64 concat, ELU ---
    convertA4_kernel<<<(N * 128 / 4 + 255) / 256, 256, 0, stream>>>(x, A2a, N * 128 / 4);
    convertW_kernel<<<(256 * 128 + 255) / 256, 256, 0, stream>>>(W1, 256, 0, 256, 256, 128, WT2);
    {
        dim3 g(MPAD / 128, 2);
        gemm_mfma_kernel<<<g, 256, 0, stream>>>(A2a, WT2, nullptr, f1b, N, 256, 128, 256, nullptr, 0);
    }
    row_alpha4_kernel<<<nwb, 256, 0, stream>>>(f1b, a1_src, a1_dst, al_s, al_d, N);
    softmax4_kernel<<<nwb, 256, 0, stream>>>(al_s, al_d, row_ptr, csr_src, wbuf, inv4, N);
    agg4_wave<<<nwb, 256, 0, stream>>>(f1b, wbuf, inv4, row_ptr, csr_src, b1, nullptr, A2b, 0, N);

    // --- layer 2: 256 -> 4x64 concat + residual, ELU ---
    convertW_kernel<<<(256 * 256 + 255) / 256, 256, 0, stream>>>(W2, 256, 0, 256, 256, 256, WT2);
    {
        dim3 g(MPAD / 128, 2);
        gemm_mfma_kernel<<<g, 256, 0, stream>>>(A2b, WT2, nullptr, f1b, N, 256, 256, 256, nullptr, 0);
    }
    row_alpha4_kernel<<<nwb, 256, 0, stream>>>(f1b, a2_src, a2_dst, al_s, al_d, N);
    softmax4_kernel<<<nwb, 256, 0, stream>>>(al_s, al_d, row_ptr, csr_src, wbuf, inv4, N);
    convertW_kernel<<<(256 * 256 + 255) / 256, 256, 0, stream>>>(Wres2, 256, 0, 256, 256, 256, WT2);
    {
        dim3 g0(C0 / 128, 2);
        gemm_mfma_kernel<<<g0, 256, 0, stream>>>(A2b, WT2, o1c, nullptr, C0, 256, 256, 256, nullptr, 0);
        agg4_wave<<<(C0 + 3) / 4, 256, 0, stream>>>(f1b, wbuf, inv4, row_ptr, csr_src, b2, o1c, o2b, 0, C0);
        dim3 g1(C1R / 128, 2);
        gemm_mfma_kernel<<<g1, 256, 0, stream>>>(A2b + (size_t)C0 * 256, WT2, o1c, nullptr,
                                                 N - C0, 256, 256, 256, nullptr, 0);
        agg4_wave<<<(N - C0 + 3) / 4, 256, 0, stream>>>(f1b, wbuf, inv4, row_ptr, csr_src, b2, o1c, o2b, C0, N - C0);
    }

    // --- layer 3: input-space aggregation + one fused GEMM ---
    prep_cmat_kernel<<<(128 * 256 + 255) / 256, 256, 0, stream>>>(W3, a3_src, a3_dst, cmT);
    {
        dim3 g(MPAD / 128, 1);
        gemm_mfma_kernel<<<g, 256, 0, stream>>>(o2b, cmT, al, nullptr, N, 12, 256, 12, nullptr, 0);
    }
    softmax6_kernel<<<nwb, 256, 0, stream>>>(al, row_ptr, csr_src, wbuf, inv6, N);
    convertW3stack_kernel<<<(128 * 1536 + 255) / 256, 256, 0, stream>>>(W3, W3sT);
    {
        aggS_wave<<<(C0 + 3) / 4, 256, 0, stream>>>(o2b, wbuf, inv6, row_ptr, csr_src, Sb, 0, C0);
        dim3 g0(C0 / 128, 1);
        gemm_mfma_kernel<<<g0, 256, 0, stream>>>(Sb, W3sT, out, nullptr, C0, 121, 1536, 121, b3, 1);
        aggS_wave<<<(N - C0 + 3) / 4, 256, 0, stream>>>(o2b, wbuf, inv6, row_ptr, csr_src, Sb, C0, N - C0);
        dim3 g1(C1R / 128, 1);
        gemm_mfma_kernel<<<g1, 256, 0, stream>>>(Sb, W3sT, out + (size_t)C0 * 121, nullptr,
                                                 N - C0, 121, 1536, 121, b3, 1);
    }
}

// Round 5
// 688.273 us; speedup vs baseline: 3.6891x; 1.0670x over previous
//
#include <hip/hip_runtime.h>
#include <hip/hip_bf16.h>

// PPI GAT, 3 layers. N=50000, E=800000 (+N self loops), avg degree ~17.
// R5: softmax fused into gather-agg (no-max exp with clamp, per-lane S, 1/S epilogue),
//     uint4 2-edge gathers, combined W2|Wres2 GEMM (bf16 residual, no L2 chunking),
//     dedicated layer-3 logit kernel.

#define NODES 50000
#define EDGES 800000
#define MPAD  50048            // ceil(N/128)*128
#define C0    25088            // layer-3 chunk-0 rows (196 tiles)
#define C1R   24960            // layer-3 chunk-1 padded rows (195 tiles)

typedef unsigned short u16;
typedef __attribute__((ext_vector_type(8))) short bf16x8;
typedef __attribute__((ext_vector_type(4))) float f32x4;

__device__ __forceinline__ float bf16f(u16 r) {
    return __uint_as_float(((unsigned)r) << 16);
}
__device__ __forceinline__ u16 f2b(float v) {
    __hip_bfloat16 b = __float2bfloat16(v);
    return *(u16*)&b;
}
__device__ __forceinline__ float blo(unsigned d) { return __uint_as_float(d << 16); }
__device__ __forceinline__ float bhi(unsigned d) { return __uint_as_float(d & 0xffff0000u); }

// ---------------- CSR build ----------------

__global__ void fill_ones_kernel(int* __restrict__ deg, int n) {
    int i = blockIdx.x * blockDim.x + threadIdx.x;
    if (i < n) deg[i] = 1;  // self-loop
}

__global__ void hist_kernel(const int* __restrict__ dst, int* __restrict__ deg, int E) {
    int e = blockIdx.x * blockDim.x + threadIdx.x;
    if (e < E) atomicAdd(&deg[dst[e]], 1);
}

__global__ void deg_bsum_kernel(const int* __restrict__ deg, int* __restrict__ bsum, int n) {
    int tid = threadIdx.x, lane = tid & 63, wid = tid >> 6;
    int i = blockIdx.x * 256 + tid;
    int v = (i < n) ? deg[i] : 0;
    #pragma unroll
    for (int ofs = 32; ofs > 0; ofs >>= 1) v += __shfl_down(v, ofs);
    __shared__ int sp[4];
    if (lane == 0) sp[wid] = v;
    __syncthreads();
    if (tid == 0) bsum[blockIdx.x] = sp[0] + sp[1] + sp[2] + sp[3];
}

__global__ void bsum_scan_kernel(int* __restrict__ bsum, int* __restrict__ row_ptr,
                                 int nb, int n) {
    int tid = threadIdx.x, lane = tid & 63, wid = tid >> 6;
    int v = (tid < nb) ? bsum[tid] : 0;
    int incl = v;
    #pragma unroll
    for (int ofs = 1; ofs < 64; ofs <<= 1) {
        int t = __shfl_up(incl, ofs);
        if (lane >= ofs) incl += t;
    }
    __shared__ int sp[4];
    if (lane == 63) sp[wid] = incl;
    __syncthreads();
    int add = 0;
    for (int k = 0; k < wid; k++) add += sp[k];
    int excl = incl - v + add;
    if (tid < nb) bsum[tid] = excl;
    if (tid == nb - 1) row_ptr[n] = excl + v;
}

__global__ void deg_scan_kernel(const int* __restrict__ deg, const int* __restrict__ bofs,
                                int* __restrict__ row_ptr, int* __restrict__ cursor, int n) {
    int tid = threadIdx.x, lane = tid & 63, wid = tid >> 6;
    int i = blockIdx.x * 256 + tid;
    int v = (i < n) ? deg[i] : 0;
    int incl = v;
    #pragma unroll
    for (int ofs = 1; ofs < 64; ofs <<= 1) {
        int t = __shfl_up(incl, ofs);
        if (lane >= ofs) incl += t;
    }
    __shared__ int sp[4];
    if (lane == 63) sp[wid] = incl;
    __syncthreads();
    int add = bofs[blockIdx.x];
    for (int k = 0; k < wid; k++) add += sp[k];
    int excl = incl - v + add;
    if (i < n) { row_ptr[i] = excl; cursor[i] = excl; }
}

__global__ void scatter_kernel(const int* __restrict__ src, const int* __restrict__ dst,
                               int E, int n, int* __restrict__ cursor, int* __restrict__ csr_src) {
    int e = blockIdx.x * blockDim.x + threadIdx.x;
    if (e < E) {
        int d = dst[e];
        int p = atomicAdd(&cursor[d], 1);
        csr_src[p] = src[e];
    } else if (e < E + n) {
        int i = e - E;
        int p = atomicAdd(&cursor[i], 1);
        csr_src[p] = i;  // self-loop
    }
}

// ---------------- converts ----------------

__global__ void convertA4_kernel(const float* __restrict__ A, u16* __restrict__ O, int total4) {
    int idx = blockIdx.x * blockDim.x + threadIdx.x;
    if (idx >= total4) return;
    float4 f = ((const float4*)A)[idx];
    ushort4 o;
    o.x = f2b(f.x); o.y = f2b(f.y); o.z = f2b(f.z); o.w = f2b(f.w);
    ((ushort4*)O)[idx] = o;
}

__global__ void convertW_kernel(const float* __restrict__ W, int ldw, int col0,
                                int Ncols, int Npad, int K, u16* __restrict__ WT) {
    int idx = blockIdx.x * blockDim.x + threadIdx.x;
    if (idx >= Npad * K) return;
    int k = idx % K;
    int n = idx / K;
    float f = (n < Ncols) ? W[(size_t)k * ldw + col0 + n] : 0.f;
    WT[(size_t)n * K + k] = f2b(f);
}

__global__ void convertW3stack_kernel(const float* __restrict__ W3, u16* __restrict__ WT) {
    int idx = blockIdx.x * blockDim.x + threadIdx.x;
    if (idx >= 128 * 1536) return;
    int q = idx % 1536;
    int n = idx / 1536;
    int h = q >> 8, k = q & 255;
    float f = (n < 121) ? W3[(size_t)k * 726 + h * 121 + n] : 0.f;
    WT[(size_t)n * 1536 + q] = f2b(f);
}

// cm[o, k] (fp32): o<6 -> sum_c W3[k,h*121+c]*a3_src[h,c] (h=o); o in 6..11 -> a3_dst (h=o-6)
__global__ void prep_cmat_kernel(const float* __restrict__ W3, const float* __restrict__ a3s,
                                 const float* __restrict__ a3d, float* __restrict__ cm) {
    int idx = blockIdx.x * blockDim.x + threadIdx.x;
    if (idx >= 12 * 256) return;
    int k = idx & 255;
    int o = idx >> 8;
    int h = (o < 6) ? o : o - 6;
    const float* a = (o < 6) ? a3s : a3d;
    float v = 0.f;
    for (int c = 0; c < 121; c++) v += W3[(size_t)k * 726 + h * 121 + c] * a[h * 121 + c];
    cm[(size_t)o * 256 + k] = v;
}

// ---------------- bf16 MFMA GEMM: C[M,Ncols] = A[M,K2] @ B[Npad,K2]^T ----------------
// Outputs: Cf fp32 (act=1: sigmoid(v+bias)), else bf16 split: col<split -> Cb, else Cb2.

__global__ __launch_bounds__(256) void gemm_mfma_kernel(
    const u16* __restrict__ A, const u16* __restrict__ B,
    float* __restrict__ Cf, u16* __restrict__ Cb, u16* __restrict__ Cb2,
    int M, int Ncols, int K2, int ldc, int split,
    const float* __restrict__ bias, int act) {
    __shared__ __align__(16) u16 As[128][40];
    __shared__ __align__(16) u16 Bs[128][40];
    int tid = threadIdx.x;
    int lane = tid & 63;
    int wv = tid >> 6;
    int quad = lane >> 4, lm = lane & 15;
    int wm = (wv & 1) * 64, wn = (wv >> 1) * 64;
    int bm = blockIdx.x * 128, bn = blockIdx.y * 128;

    f32x4 zero = {0.f, 0.f, 0.f, 0.f};
    f32x4 acc[4][4];
    #pragma unroll
    for (int i = 0; i < 4; i++)
        #pragma unroll
        for (int j = 0; j < 4; j++) acc[i][j] = zero;

    for (int k0 = 0; k0 < K2; k0 += 32) {
        #pragma unroll
        for (int it = 0; it < 2; ++it) {
            int chunk = tid + it * 256;
            int row = chunk >> 2, seg = chunk & 3;
            uint4 va = *(const uint4*)(A + (size_t)(bm + row) * K2 + k0 + seg * 8);
            uint4 vb = *(const uint4*)(B + (size_t)(bn + row) * K2 + k0 + seg * 8);
            *(uint4*)&As[row][seg * 8] = va;
            *(uint4*)&Bs[row][seg * 8] = vb;
        }
        __syncthreads();
        bf16x8 af[4], bfr[4];
        #pragma unroll
        for (int i = 0; i < 4; i++) af[i] = *(const bf16x8*)&As[wm + i * 16 + lm][quad * 8];
        #pragma unroll
        for (int j = 0; j < 4; j++) bfr[j] = *(const bf16x8*)&Bs[wn + j * 16 + lm][quad * 8];
        #pragma unroll
        for (int i = 0; i < 4; i++)
            #pragma unroll
            for (int j = 0; j < 4; j++)
                acc[i][j] = __builtin_amdgcn_mfma_f32_16x16x32_bf16(af[i], bfr[j], acc[i][j], 0, 0, 0);
        __syncthreads();
    }

    // C/D layout: col = lane&15, row = quad*4 + reg
    #pragma unroll
    for (int i = 0; i < 4; i++) {
        #pragma unroll
        for (int j = 0; j < 4; j++) {
            int col = bn + wn + j * 16 + lm;
            if (col >= Ncols) continue;
            int row_base = bm + wm + i * 16 + quad * 4;
            #pragma unroll
            for (int r = 0; r < 4; r++) {
                int row = row_base + r;
                if (row >= M) continue;
                float v = acc[i][j][r];
                if (act == 1) {
                    v += bias[col];
                    v = 1.f / (1.f + __expf(-v));
                    Cf[(size_t)row * ldc + col] = v;
                } else if (col < split) {
                    Cb[(size_t)row * ldc + col] = f2b(v);
                } else {
                    Cb2[(size_t)row * ldc + col - split] = f2b(v);
                }
            }
        }
    }
}

// ---------------- attention logits, layers 1&2 ----------------

__global__ void row_alpha4_kernel(const u16* __restrict__ f, const float* __restrict__ a_s,
                                  const float* __restrict__ a_d, float* __restrict__ al_s,
                                  float* __restrict__ al_d, int n) {
    int wv = threadIdx.x >> 6, lane = threadIdx.x & 63;
    int i = blockIdx.x * 4 + wv;
    if (i >= n) return;
    ushort4 hv = *(const ushort4*)(f + (size_t)i * 256 + lane * 4);
    float4 as = *(const float4*)(a_s + lane * 4);
    float4 ad = *(const float4*)(a_d + lane * 4);
    float x0 = bf16f(hv.x), x1 = bf16f(hv.y), x2 = bf16f(hv.z), x3 = bf16f(hv.w);
    float ps = x0 * as.x + x1 * as.y + x2 * as.z + x3 * as.w;
    float pd = x0 * ad.x + x1 * ad.y + x2 * ad.z + x3 * ad.w;
    #pragma unroll
    for (int ofs = 1; ofs < 16; ofs <<= 1) {
        ps += __shfl_xor(ps, ofs);
        pd += __shfl_xor(pd, ofs);
    }
    if ((lane & 15) == 0) {
        int hd = lane >> 4;
        al_s[(size_t)i * 4 + hd] = ps;
        al_d[(size_t)i * 4 + hd] = pd;
    }
}

// layer-3 logits: al3[i, 0..5] = o2b[i]·cm_src, al3[i, 6..11] = o2b[i]·cm_dst
__global__ __launch_bounds__(256) void al3_kernel(const u16* __restrict__ o2b,
                                                  const float* __restrict__ cm,
                                                  float* __restrict__ al3, int n) {
    int wid = threadIdx.x >> 6, lane = threadIdx.x & 63;
    int i = blockIdx.x * 4 + wid;
    if (i >= n) return;
    uint2 d = *(const uint2*)(o2b + (size_t)i * 256 + lane * 4);
    float v0 = blo(d.x), v1 = bhi(d.x), v2 = blo(d.y), v3 = bhi(d.y);
    float a[12];
    #pragma unroll
    for (int o = 0; o < 12; o++) {
        float4 c = *(const float4*)(cm + (size_t)o * 256 + lane * 4);
        a[o] = v0 * c.x + v1 * c.y + v2 * c.z + v3 * c.w;
    }
    #pragma unroll
    for (int ofs = 1; ofs < 64; ofs <<= 1) {
        #pragma unroll
        for (int o = 0; o < 12; o++) a[o] += __shfl_xor(a[o], ofs);
    }
    if (lane == 0) {
        float4* dst = (float4*)(al3 + (size_t)i * 12);
        dst[0] = make_float4(a[0], a[1], a[2], a[3]);
        dst[1] = make_float4(a[4], a[5], a[6], a[7]);
        dst[2] = make_float4(a[8], a[9], a[10], a[11]);
    }
}

// ---------------- fused softmax+agg, layers 1&2: WAVE per node ----------------
// Lanes 0-31 even edges / 32-63 odd edges; each lane 8 channels (uint4 gather).
// ex = exp(clamp(leaky(al_s[src]+al_d[i]),60)) staged per (head=lane>>4, edge=lane&15),
// broadcast via shfl; S accumulated per lane (single head per lane, no reduction).

__global__ __launch_bounds__(256) void agg4_fused(
    const u16* __restrict__ f, const float* __restrict__ al_s, const float* __restrict__ al_d,
    const int* __restrict__ row_ptr, const int* __restrict__ csr_src,
    const float* __restrict__ bias, const u16* __restrict__ resb,
    u16* __restrict__ outb, int n) {
    int wid = threadIdx.x >> 6, lane = threadIdx.x & 63;
    int i = blockIdx.x * 4 + wid;
    if (i >= n) return;
    int beg = row_ptr[i], end = row_ptr[i + 1];
    int h_st = lane >> 4;        // staging head
    int el = lane & 15;          // staging edge slot
    int half = lane >> 5;        // edge parity
    int c8 = (lane & 31) * 8;    // this lane's 8 channels
    float ald_st = al_d[(size_t)i * 4 + h_st];
    float acc[8] = {};
    float S = 0.f;
    for (int base = beg; base < end; base += 16) {
        int cnt = min(16, end - base);
        int idxv = csr_src[base + min(el, cnt - 1)];
        float av = al_s[(size_t)idxv * 4 + h_st] + ald_st;
        av = av > 0.f ? av : 0.2f * av;
        float ex = __expf(fminf(av, 60.f));
        for (int e = 0; e < cnt; e += 2) {
            int ei = e + half;
            int eu = ei < cnt ? ei : e;
            int s = __shfl(idxv, eu);
            float w = __shfl(ex, ((lane & 24) << 1) | eu);
            if (ei >= cnt) w = 0.f;
            S += w;
            uint4 d = *(const uint4*)(f + (size_t)s * 256 + c8);
            acc[0] = fmaf(w, blo(d.x), acc[0]); acc[1] = fmaf(w, bhi(d.x), acc[1]);
            acc[2] = fmaf(w, blo(d.y), acc[2]); acc[3] = fmaf(w, bhi(d.y), acc[3]);
            acc[4] = fmaf(w, blo(d.z), acc[4]); acc[5] = fmaf(w, bhi(d.z), acc[5]);
            acc[6] = fmaf(w, blo(d.w), acc[6]); acc[7] = fmaf(w, bhi(d.w), acc[7]);
        }
    }
    #pragma unroll
    for (int k = 0; k < 8; k++) acc[k] += __shfl_xor(acc[k], 32);
    S += __shfl_xor(S, 32);
    if (half == 0) {
        float inv = 1.f / (S + 1e-16f);
        float4 b0 = *(const float4*)(bias + c8);
        float4 b1 = *(const float4*)(bias + c8 + 4);
        float v[8];
        v[0] = acc[0] * inv + b0.x; v[1] = acc[1] * inv + b0.y;
        v[2] = acc[2] * inv + b0.z; v[3] = acc[3] * inv + b0.w;
        v[4] = acc[4] * inv + b1.x; v[5] = acc[5] * inv + b1.y;
        v[6] = acc[6] * inv + b1.z; v[7] = acc[7] * inv + b1.w;
        if (resb) {
            uint4 r = *(const uint4*)(resb + (size_t)i * 256 + c8);
            v[0] += blo(r.x); v[1] += bhi(r.x); v[2] += blo(r.y); v[3] += bhi(r.y);
            v[4] += blo(r.z); v[5] += bhi(r.z); v[6] += blo(r.w); v[7] += bhi(r.w);
        }
        #pragma unroll
        for (int k = 0; k < 8; k++) v[k] = v[k] > 0.f ? v[k] : (__expf(v[k]) - 1.f);  // ELU
        uint4 o;
        o.x = (unsigned)f2b(v[0]) | ((unsigned)f2b(v[1]) << 16);
        o.y = (unsigned)f2b(v[2]) | ((unsigned)f2b(v[3]) << 16);
        o.z = (unsigned)f2b(v[4]) | ((unsigned)f2b(v[5]) << 16);
        o.w = (unsigned)f2b(v[6]) | ((unsigned)f2b(v[7]) << 16);
        *(uint4*)(outb + (size_t)i * 256 + c8) = o;
    }
}

// ---------------- fused softmax+agg, layer 3 (6 heads): WAVE per node ----------------
// S[li, h*256+c] = (1/(6*Sum_h)) * sum_j ex_jh * x[src_j, c]

__global__ __launch_bounds__(256) void aggS_fused(
    const u16* __restrict__ x, const float* __restrict__ al3,
    const int* __restrict__ row_ptr, const int* __restrict__ csr_src,
    u16* __restrict__ S, int node0, int count) {
    __shared__ int s_i[4][16];
    __shared__ float s_w[4][96];
    int wid = threadIdx.x >> 6, lane = threadIdx.x & 63;
    int li = blockIdx.x * 4 + wid;
    if (li >= count) return;
    int i = node0 + li;
    int beg = row_ptr[i], end = row_ptr[i + 1];
    int c4 = lane * 4;
    int e16 = lane & 15;
    int hA = lane >> 4;            // heads 0-3
    int hB = 4 + (lane >> 4);      // heads 4-5 (lanes 0-31)
    float aldA = al3[(size_t)i * 12 + 6 + hA];
    float aldB = (lane < 32) ? al3[(size_t)i * 12 + 6 + hB] : 0.f;
    float acc[6][4] = {};
    float Ssum[6] = {};
    for (int base = beg; base < end; base += 16) {
        int cnt = min(16, end - base);
        int idxe = csr_src[base + min(e16, cnt - 1)];
        if (lane < 16) s_i[wid][lane] = idxe;
        float vA = al3[(size_t)idxe * 12 + hA] + aldA;
        vA = vA > 0.f ? vA : 0.2f * vA;
        float exA = __expf(fminf(vA, 60.f));
        if (e16 < cnt) s_w[wid][e16 * 6 + hA] = exA;
        if (lane < 32) {
            float vB = al3[(size_t)idxe * 12 + hB] + aldB;
            vB = vB > 0.f ? vB : 0.2f * vB;
            float exB = __expf(fminf(vB, 60.f));
            if (e16 < cnt) s_w[wid][e16 * 6 + hB] = exB;
        }
        for (int e = 0; e < cnt; e++) {
            int s = s_i[wid][e];
            uint2 d = *(const uint2*)(x + (size_t)s * 256 + c4);
            float v0 = blo(d.x), v1 = bhi(d.x), v2 = blo(d.y), v3 = bhi(d.y);
            #pragma unroll
            for (int hh = 0; hh < 6; hh++) {
                float w = s_w[wid][e * 6 + hh];
                Ssum[hh] += w;
                acc[hh][0] = fmaf(w, v0, acc[hh][0]);
                acc[hh][1] = fmaf(w, v1, acc[hh][1]);
                acc[hh][2] = fmaf(w, v2, acc[hh][2]);
                acc[hh][3] = fmaf(w, v3, acc[hh][3]);
            }
        }
    }
    #pragma unroll
    for (int hh = 0; hh < 6; hh++) {
        float inv = 1.f / (6.f * (Ssum[hh] + 1e-16f));
        ushort4 o;
        o.x = f2b(acc[hh][0] * inv);
        o.y = f2b(acc[hh][1] * inv);
        o.z = f2b(acc[hh][2] * inv);
        o.w = f2b(acc[hh][3] * inv);
        *(ushort4*)(S + (size_t)li * 1536 + hh * 256 + c4) = o;
    }
}

// ---------------- host ----------------

extern "C" void kernel_launch(void* const* d_in, const int* in_sizes, int n_in,
                              void* d_out, int out_size, void* d_ws, size_t ws_size,
                              hipStream_t stream) {
    const float* x      = (const float*)d_in[0];
    const int*   src    = (const int*)d_in[1];
    const int*   dst    = (const int*)d_in[2];
    const float* W1     = (const float*)d_in[3];
    const float* a1_src = (const float*)d_in[4];
    const float* a1_dst = (const float*)d_in[5];
    const float* b1     = (const float*)d_in[6];
    const float* W2     = (const float*)d_in[7];
    const float* a2_src = (const float*)d_in[8];
    const float* a2_dst = (const float*)d_in[9];
    const float* b2     = (const float*)d_in[10];
    const float* Wres2  = (const float*)d_in[11];
    const float* W3     = (const float*)d_in[12];
    const float* a3_src = (const float*)d_in[13];
    const float* a3_dst = (const float*)d_in[14];
    const float* b3     = (const float*)d_in[15];
    float* out = (float*)d_out;

    const int N = NODES, E = EDGES;
    const int EN = E + N;
    const int NB = (N + 255) / 256;  // 196

    char* p = (char*)d_ws;
    auto alloc = [&](size_t bytes) -> char* {
        char* r = p;
        p += (bytes + 511) & ~(size_t)511;
        return r;
    };
    // persistent
    int*   row_ptr = (int*)alloc((size_t)(N + 1) * sizeof(int));
    int*   cursor  = (int*)alloc((size_t)N * sizeof(int));
    int*   deg     = (int*)alloc((size_t)N * sizeof(int));
    int*   bsum    = (int*)alloc(256 * sizeof(int));
    int*   csr_src = (int*)alloc((size_t)EN * sizeof(int));
    float* al      = (float*)alloc((size_t)N * 12 * sizeof(float));  // L1/2: al_s(4N)+al_d(4N); L3: al3 12N
    float* cm      = (float*)alloc((size_t)12 * 256 * sizeof(float));
    u16*   o2b     = (u16*)alloc((size_t)MPAD * 256 * sizeof(u16));
    u16*   WT2     = (u16*)alloc((size_t)512 * 256 * sizeof(u16));
    u16*   W3sT    = (u16*)alloc((size_t)128 * 1536 * sizeof(u16));
    // region2 (phase-overlaid)
    const size_t A2B_B  = (size_t)MPAD * 256 * sizeof(u16);
    const size_t F1B_B  = (size_t)N * 256 * sizeof(u16);
    const size_t RESB_B = (size_t)N * 256 * sizeof(u16);
    const size_t S_B    = (size_t)C0 * 1536 * sizeof(u16);
    size_t r2_bytes = A2B_B + F1B_B + RESB_B;
    if (S_B > r2_bytes) r2_bytes = S_B;
    char* r2 = alloc(r2_bytes + 1024);
    u16* A2b  = (u16*)r2;                        // layer-1 out bf16 [MPAD,256]
    u16* f1b  = (u16*)(r2 + A2B_B);              // layer feat bf16 [N,256]
    u16* resb = (u16*)(r2 + A2B_B + F1B_B);      // layer-2 residual bf16 [N,256]
    u16* A2a  = (u16*)(r2 + A2B_B + F1B_B);      // x bf16 [MPAD,128] (dead before resb)
    u16* Sb   = (u16*)r2;                        // S chunk bf16 [C0,1536] (layer 3)
    (void)ws_size; (void)n_in; (void)in_sizes; (void)out_size;

    float* al_s = al;
    float* al_d = al + (size_t)4 * N;

    // --- CSR build ---
    fill_ones_kernel<<<NB, 256, 0, stream>>>(deg, N);
    hist_kernel<<<(E + 255) / 256, 256, 0, stream>>>(dst, deg, E);
    deg_bsum_kernel<<<NB, 256, 0, stream>>>(deg, bsum, N);
    bsum_scan_kernel<<<1, 256, 0, stream>>>(bsum, row_ptr, NB, N);
    deg_scan_kernel<<<NB, 256, 0, stream>>>(deg, bsum, row_ptr, cursor, N);
    scatter_kernel<<<(E + N + 255) / 256, 256, 0, stream>>>(src, dst, E, N, cursor, csr_src);

    int nwb = (N + 3) / 4;

    // --- layer 1: 128 -> 4x64 concat, ELU ---
    convertA4_kernel<<<(N * 128 / 4 + 255) / 256, 256, 0, stream>>>(x, A2a, N * 128 / 4);
    convertW_kernel<<<(256 * 128 + 255) / 256, 256, 0, stream>>>(W1, 256, 0, 256, 256, 128, WT2);
    {
        dim3 g(MPAD / 128, 2);
        gemm_mfma_kernel<<<g, 256, 0, stream>>>(A2a, WT2, nullptr, f1b, nullptr,
                                                N, 256, 128, 256, 9999, nullptr, 0);
    }
    row_alpha4_kernel<<<nwb, 256, 0, stream>>>(f1b, a1_src, a1_dst, al_s, al_d, N);
    agg4_fused<<<nwb, 256, 0, stream>>>(f1b, al_s, al_d, row_ptr, csr_src, b1, nullptr, A2b, N);

    // --- layer 2: 256 -> 4x64 concat + residual (one 512-wide GEMM), ELU ---
    convertW_kernel<<<(256 * 256 + 255) / 256, 256, 0, stream>>>(W2, 256, 0, 256, 256, 256, WT2);
    convertW_kernel<<<(256 * 256 + 255) / 256, 256, 0, stream>>>(Wres2, 256, 0, 256, 256, 256,
                                                                 WT2 + (size_t)256 * 256);
    {
        dim3 g(MPAD / 128, 4);
        gemm_mfma_kernel<<<g, 256, 0, stream>>>(A2b, WT2, nullptr, f1b, resb,
                                                N, 512, 256, 256, 256, nullptr, 0);
    }
    row_alpha4_kernel<<<nwb, 256, 0, stream>>>(f1b, a2_src, a2_dst, al_s, al_d, N);
    agg4_fused<<<nwb, 256, 0, stream>>>(f1b, al_s, al_d, row_ptr, csr_src, b2, resb, o2b, N);

    // --- layer 3: logits -> fused softmax+input-space agg -> one fused GEMM ---
    prep_cmat_kernel<<<(12 * 256 + 255) / 256, 256, 0, stream>>>(W3, a3_src, a3_dst, cm);
    al3_kernel<<<nwb, 256, 0, stream>>>(o2b, cm, al, N);
    convertW3stack_kernel<<<(128 * 1536 + 255) / 256, 256, 0, stream>>>(W3, W3sT);
    {
        aggS_fused<<<(C0 + 3) / 4, 256, 0, stream>>>(o2b, al, row_ptr, csr_src, Sb, 0, C0);
        dim3 g0(C0 / 128, 1);
        gemm_mfma_kernel<<<g0, 256, 0, stream>>>(Sb, W3sT, out, nullptr, nullptr,
                                                 C0, 121, 1536, 121, 9999, b3, 1);
        aggS_fused<<<(N - C0 + 3) / 4, 256, 0, stream>>>(o2b, al, row_ptr, csr_src, Sb, C0, N - C0);
        dim3 g1(C1R / 128, 1);
        gemm_mfma_kernel<<<g1, 256, 0, stream>>>(Sb, W3sT, out + (size_t)C0 * 121, nullptr, nullptr,
                                                 N - C0, 121, 1536, 121, 9999, b3, 1);
    }
}